// Round 1
// baseline (5810.487 us; speedup 1.0000x reference)
//
#include <hip/hip_runtime.h>

#define NN 50000
#define NREL 3
#define NE 500000
#define DIN 128
#define DHID 256
#define DOUT 128

// ---------------- degree ----------------
__global__ __launch_bounds__(256) void deg_kernel(const int* __restrict__ dst,
                                                  float* __restrict__ deg) {
    int t = blockIdx.x * 256 + threadIdx.x;
    if (t >= NREL * NE) return;
    int r = t / NE;
    atomicAdd(&deg[r * NN + dst[t]], 1.0f);
}

__global__ __launch_bounds__(256) void invert_kernel(float* __restrict__ deg, int n) {
    int t = blockIdx.x * 256 + threadIdx.x;
    if (t < n) deg[t] = 1.0f / fmaxf(deg[t], 1.0f);
}

// out[i] = in[i] + in[sz+i] + in[2sz+i]   (sum weights/bias over relations)
__global__ __launch_bounds__(256) void sum3_kernel(const float* __restrict__ in,
                                                   float* __restrict__ out, int sz) {
    int t = blockIdx.x * 256 + threadIdx.x;
    if (t < sz) out[t] = in[t] + in[sz + t] + in[2 * sz + t];
}

// out[n*d + j] = bias[j]
__global__ __launch_bounds__(256) void init_bias_kernel(float* __restrict__ out,
                                                        const float* __restrict__ bias,
                                                        int total, int d) {
    int t = blockIdx.x * 256 + threadIdx.x;
    if (t < total) out[t] = bias[t % d];
}

__global__ __launch_bounds__(256) void relu_kernel(float* __restrict__ p, int n) {
    int t = blockIdx.x * 256 + threadIdx.x;
    if (t < n) p[t] = fmaxf(p[t], 0.0f);
}

// out[dst] += feat[src] * invdeg[dst]; feat rows are 128 floats.
// 32 threads per edge, float4 per thread.
__global__ __launch_bounds__(256) void scatter_mean_kernel(
    const float* __restrict__ feat, const int* __restrict__ src,
    const int* __restrict__ dst, const float* __restrict__ invdeg,
    float* __restrict__ out) {
    int t = blockIdx.x * 256 + threadIdx.x;
    int e = t >> 5;
    if (e >= NE) return;
    int lane = t & 31;
    int s = src[e];
    int d = dst[e];
    float w = invdeg[d];
    float4 v = *(const float4*)(feat + (size_t)s * 128 + lane * 4);
    float* po = out + (size_t)d * 128 + lane * 4;
    atomicAdd(po + 0, v.x * w);
    atomicAdd(po + 1, v.y * w);
    atomicAdd(po + 2, v.z * w);
    atomicAdd(po + 3, v.w * w);
}

// ---------------- fp32 GEMM: C[M,N] (+)= A[M,K] @ B[K,N] ----------------
// BM=128, BN=128, BK=16, 256 threads, 8x8 per thread.
// Requires: K % 16 == 0, N % 128 == 0 (true here: K in {128,256}, N in {128,256}).
#define BM 128
#define BN 128
#define BK 16

__global__ __launch_bounds__(256) void gemm_acc_kernel(
    const float* __restrict__ A, const float* __restrict__ B, float* __restrict__ C,
    int M, int K, int N, int accumulate) {
    __shared__ float As[BK][BM + 1];
    __shared__ float Bs[BK][BN + 1];

    int tid = threadIdx.x;
    int tx = tid & 15;        // 0..15 -> col group
    int ty = tid >> 4;        // 0..15 -> row group
    int bm = blockIdx.x * BM;
    int bn = blockIdx.y * BN;

    float acc[8][8];
#pragma unroll
    for (int i = 0; i < 8; ++i)
#pragma unroll
        for (int j = 0; j < 8; ++j) acc[i][j] = 0.0f;

    // A-load mapping: thread t loads row m = t>>1, k-offset kk = (t&1)*8 (two float4)
    int a_m = tid >> 1;
    int a_kk = (tid & 1) * 8;
    // B-load mapping: thread t loads k = t>>4, n-offset n8 = (t&15)*8 (two float4)
    int b_k = tid >> 4;
    int b_n8 = (tid & 15) * 8;

    for (int k0 = 0; k0 < K; k0 += BK) {
        // load A tile (transposed into LDS)
        {
            int gm = bm + a_m;
            float4 v0, v1;
            if (gm < M) {
                const float* ap = A + (size_t)gm * K + k0 + a_kk;
                v0 = *(const float4*)(ap);
                v1 = *(const float4*)(ap + 4);
            } else {
                v0 = make_float4(0.f, 0.f, 0.f, 0.f);
                v1 = v0;
            }
            As[a_kk + 0][a_m] = v0.x;
            As[a_kk + 1][a_m] = v0.y;
            As[a_kk + 2][a_m] = v0.z;
            As[a_kk + 3][a_m] = v0.w;
            As[a_kk + 4][a_m] = v1.x;
            As[a_kk + 5][a_m] = v1.y;
            As[a_kk + 6][a_m] = v1.z;
            As[a_kk + 7][a_m] = v1.w;
        }
        // load B tile
        {
            const float* bp = B + (size_t)(k0 + b_k) * N + bn + b_n8;
            float4 v0 = *(const float4*)(bp);
            float4 v1 = *(const float4*)(bp + 4);
            Bs[b_k][b_n8 + 0] = v0.x;
            Bs[b_k][b_n8 + 1] = v0.y;
            Bs[b_k][b_n8 + 2] = v0.z;
            Bs[b_k][b_n8 + 3] = v0.w;
            Bs[b_k][b_n8 + 4] = v1.x;
            Bs[b_k][b_n8 + 5] = v1.y;
            Bs[b_k][b_n8 + 6] = v1.z;
            Bs[b_k][b_n8 + 7] = v1.w;
        }
        __syncthreads();

#pragma unroll
        for (int k = 0; k < BK; ++k) {
            float a[8], b[8];
#pragma unroll
            for (int i = 0; i < 8; ++i) a[i] = As[k][ty + i * 16];
#pragma unroll
            for (int j = 0; j < 8; ++j) b[j] = Bs[k][tx + j * 16];
#pragma unroll
            for (int i = 0; i < 8; ++i)
#pragma unroll
                for (int j = 0; j < 8; ++j) acc[i][j] = fmaf(a[i], b[j], acc[i][j]);
        }
        __syncthreads();
    }

#pragma unroll
    for (int i = 0; i < 8; ++i) {
        int gm = bm + ty + i * 16;
        if (gm >= M) continue;
#pragma unroll
        for (int j = 0; j < 8; ++j) {
            int gn = bn + tx + j * 16;
            float* cp = C + (size_t)gm * N + gn;
            if (accumulate) *cp += acc[i][j];
            else *cp = acc[i][j];
        }
    }
}

// ---------------- launch ----------------
extern "C" void kernel_launch(void* const* d_in, const int* in_sizes, int n_in,
                              void* d_out, int out_size, void* d_ws, size_t ws_size,
                              hipStream_t stream) {
    const float* x       = (const float*)d_in[0];
    const int*   src     = (const int*)d_in[1];   // [3, NE]
    const int*   dst     = (const int*)d_in[2];   // [3, NE]
    const float* w_self1 = (const float*)d_in[3]; // [3,128,256]
    const float* w_neigh1= (const float*)d_in[4];
    const float* b1      = (const float*)d_in[5]; // [3,256]
    const float* w_self2 = (const float*)d_in[6]; // [3,256,128]
    const float* w_neigh2= (const float*)d_in[7];
    const float* b2      = (const float*)d_in[8]; // [3,128]
    float* out = (float*)d_out;

    // workspace carve-up (floats), ~78 MB total
    float* ws = (float*)d_ws;
    size_t off = 0;
    auto alloc = [&](size_t n) { float* p = ws + off; off += (n + 63) & ~(size_t)63; return p; };
    float* inv_deg = alloc(NREL * NN);     // deg then inverted in place
    float* wsum1   = alloc(DIN * DHID);
    float* bsum1   = alloc(DHID);
    float* wsum2   = alloc(DHID * DOUT);
    float* bsum2   = alloc(DOUT);
    float* agg     = alloc((size_t)NN * DIN);  // layer-1 hn_r / layer-2 y_r buffer
    float* H       = alloc((size_t)NN * DHID);

    // degrees
    hipMemsetAsync(inv_deg, 0, NREL * NN * sizeof(float), stream);
    deg_kernel<<<(NREL * NE + 255) / 256, 256, 0, stream>>>(dst, inv_deg);
    invert_kernel<<<(NREL * NN + 255) / 256, 256, 0, stream>>>(inv_deg, NREL * NN);

    // summed self-weights / biases
    sum3_kernel<<<(DIN * DHID + 255) / 256, 256, 0, stream>>>(w_self1, wsum1, DIN * DHID);
    sum3_kernel<<<(DHID + 255) / 256, 256, 0, stream>>>(b1, bsum1, DHID);
    sum3_kernel<<<(DHID * DOUT + 255) / 256, 256, 0, stream>>>(w_self2, wsum2, DHID * DOUT);
    sum3_kernel<<<(DOUT + 255) / 256, 256, 0, stream>>>(b2, bsum2, DOUT);

    // ---- layer 1: H = relu(x@wsum1 + sum_r (mean_agg_r(x))@wn1_r + bsum1)
    init_bias_kernel<<<((NN * DHID) + 255) / 256, 256, 0, stream>>>(H, bsum1, NN * DHID, DHID);
    {
        dim3 grid((NN + BM - 1) / BM, DHID / BN);
        gemm_acc_kernel<<<grid, 256, 0, stream>>>(x, wsum1, H, NN, DIN, DHID, 1);
    }
    for (int r = 0; r < NREL; ++r) {
        hipMemsetAsync(agg, 0, (size_t)NN * DIN * sizeof(float), stream);
        scatter_mean_kernel<<<(NE * 32) / 256, 256, 0, stream>>>(
            x, src + (size_t)r * NE, dst + (size_t)r * NE, inv_deg + (size_t)r * NN, agg);
        dim3 grid((NN + BM - 1) / BM, DHID / BN);
        gemm_acc_kernel<<<grid, 256, 0, stream>>>(agg, w_neigh1 + (size_t)r * DIN * DHID,
                                                  H, NN, DIN, DHID, 1);
    }
    relu_kernel<<<((NN * DHID) + 255) / 256, 256, 0, stream>>>(H, NN * DHID);

    // ---- layer 2: out = H@wsum2 + sum_r mean_agg_r(H@wn2_r) + bsum2
    init_bias_kernel<<<((NN * DOUT) + 255) / 256, 256, 0, stream>>>(out, bsum2, NN * DOUT, DOUT);
    {
        dim3 grid((NN + BM - 1) / BM, DOUT / BN);
        gemm_acc_kernel<<<grid, 256, 0, stream>>>(H, wsum2, out, NN, DHID, DOUT, 1);
    }
    for (int r = 0; r < NREL; ++r) {
        dim3 grid((NN + BM - 1) / BM, DOUT / BN);
        gemm_acc_kernel<<<grid, 256, 0, stream>>>(H, w_neigh2 + (size_t)r * DHID * DOUT,
                                                  agg, NN, DHID, DOUT, 0);
        scatter_mean_kernel<<<(NE * 32) / 256, 256, 0, stream>>>(
            agg, src + (size_t)r * NE, dst + (size_t)r * NE, inv_deg + (size_t)r * NN, out);
    }
}

// Round 2
// 1303.909 us; speedup vs baseline: 4.4562x; 4.4562x over previous
//
#include <hip/hip_runtime.h>

#define NN 50000
#define NREL 3
#define NE 500000
#define DIN 128
#define DHID 256
#define DOUT 128

// ---------------- CSR build ----------------
__global__ __launch_bounds__(256) void deg_kernel(const int* __restrict__ dst,
                                                  int* __restrict__ deg) {
    int t = blockIdx.x * 256 + threadIdx.x;
    if (t >= NREL * NE) return;
    int r = t / NE;
    atomicAdd(&deg[r * NN + dst[t]], 1);
}

// one block per relation; exclusive scan of deg -> offs
__global__ __launch_bounds__(256) void scan_kernel(const int* __restrict__ deg,
                                                   int* __restrict__ offs) {
    __shared__ int buf[256];
    int r = blockIdx.x;
    const int* d = deg + r * NN;
    int* o = offs + r * NN;
    int carry = 0;
    for (int base = 0; base < NN; base += 256) {
        int i = base + threadIdx.x;
        int v = (i < NN) ? d[i] : 0;
        buf[threadIdx.x] = v;
        __syncthreads();
        for (int s = 1; s < 256; s <<= 1) {
            int t = (threadIdx.x >= s) ? buf[threadIdx.x - s] : 0;
            __syncthreads();
            buf[threadIdx.x] += t;
            __syncthreads();
        }
        if (i < NN) o[i] = carry + buf[threadIdx.x] - v;  // exclusive
        carry += buf[255];
        __syncthreads();
    }
}

__global__ __launch_bounds__(256) void fill_kernel(const int* __restrict__ src,
                                                   const int* __restrict__ dst,
                                                   int* __restrict__ cursor,
                                                   int* __restrict__ srclist) {
    int t = blockIdx.x * 256 + threadIdx.x;
    if (t >= NREL * NE) return;
    int r = t / NE;
    int d = dst[t];
    int pos = atomicAdd(&cursor[r * NN + d], 1);  // pos is relation-local
    srclist[(size_t)r * NE + pos] = src[t];
}

// ---------------- small helpers ----------------
__global__ __launch_bounds__(256) void sum3_kernel(const float* __restrict__ in,
                                                   float* __restrict__ out, int sz) {
    int t = blockIdx.x * 256 + threadIdx.x;
    if (t < sz) out[t] = in[t] + in[sz + t] + in[2 * sz + t];
}

__global__ __launch_bounds__(256) void init_bias_kernel(float* __restrict__ out,
                                                        const float* __restrict__ bias,
                                                        int total, int d) {
    int t = blockIdx.x * 256 + threadIdx.x;
    if (t < total) out[t] = bias[t % d];
}

__global__ __launch_bounds__(256) void relu_kernel(float* __restrict__ p, int n) {
    int t = blockIdx.x * 256 + threadIdx.x;
    if (t < n) p[t] = fmaxf(p[t], 0.0f);
}

// ---------------- gather-mean: one wave per node ----------------
// out[node, 0:128] (=|+=) mean over CSR row of feat[src, 0:128]
__global__ __launch_bounds__(256) void gather_mean_kernel(
    const float* __restrict__ feat, const int* __restrict__ offs,
    const int* __restrict__ deg, const int* __restrict__ srclist,
    float* __restrict__ out, int accumulate) {
    int node = blockIdx.x * 4 + (threadIdx.x >> 6);
    if (node >= NN) return;
    int lane = threadIdx.x & 63;
    int beg = offs[node];
    int d = deg[node];

    float2 acc = make_float2(0.f, 0.f);
    for (int i = 0; i < d; i += 64) {
        int sid = (i + lane < d) ? srclist[beg + i + lane] : 0;
        int m = (d - i < 64) ? (d - i) : 64;
        for (int j = 0; j < m; ++j) {
            int s = __shfl(sid, j);
            float2 v = *(const float2*)(feat + (size_t)s * 128 + lane * 2);
            acc.x += v.x;
            acc.y += v.y;
        }
    }
    float inv = 1.0f / fmaxf((float)d, 1.0f);
    float* po = out + (size_t)node * 128 + lane * 2;
    if (accumulate) {
        po[0] += acc.x * inv;
        po[1] += acc.y * inv;
    } else {
        po[0] = acc.x * inv;
        po[1] = acc.y * inv;
    }
}

// ---------------- fp32 GEMM: C[M,N] (+)= A[M,K] @ B[K,N] ----------------
#define BM 128
#define BN 128
#define BK 16

__global__ __launch_bounds__(256) void gemm_acc_kernel(
    const float* __restrict__ A, const float* __restrict__ B, float* __restrict__ C,
    int M, int K, int N, int accumulate) {
    __shared__ float As[BK][BM + 1];
    __shared__ float Bs[BK][BN + 1];

    int tid = threadIdx.x;
    int tx = tid & 15;
    int ty = tid >> 4;
    int bm = blockIdx.x * BM;
    int bn = blockIdx.y * BN;

    float acc[8][8];
#pragma unroll
    for (int i = 0; i < 8; ++i)
#pragma unroll
        for (int j = 0; j < 8; ++j) acc[i][j] = 0.0f;

    int a_m = tid >> 1;
    int a_kk = (tid & 1) * 8;
    int b_k = tid >> 4;
    int b_n8 = (tid & 15) * 8;

    for (int k0 = 0; k0 < K; k0 += BK) {
        {
            int gm = bm + a_m;
            float4 v0, v1;
            if (gm < M) {
                const float* ap = A + (size_t)gm * K + k0 + a_kk;
                v0 = *(const float4*)(ap);
                v1 = *(const float4*)(ap + 4);
            } else {
                v0 = make_float4(0.f, 0.f, 0.f, 0.f);
                v1 = v0;
            }
            As[a_kk + 0][a_m] = v0.x;
            As[a_kk + 1][a_m] = v0.y;
            As[a_kk + 2][a_m] = v0.z;
            As[a_kk + 3][a_m] = v0.w;
            As[a_kk + 4][a_m] = v1.x;
            As[a_kk + 5][a_m] = v1.y;
            As[a_kk + 6][a_m] = v1.z;
            As[a_kk + 7][a_m] = v1.w;
        }
        {
            const float* bp = B + (size_t)(k0 + b_k) * N + bn + b_n8;
            float4 v0 = *(const float4*)(bp);
            float4 v1 = *(const float4*)(bp + 4);
            Bs[b_k][b_n8 + 0] = v0.x;
            Bs[b_k][b_n8 + 1] = v0.y;
            Bs[b_k][b_n8 + 2] = v0.z;
            Bs[b_k][b_n8 + 3] = v0.w;
            Bs[b_k][b_n8 + 4] = v1.x;
            Bs[b_k][b_n8 + 5] = v1.y;
            Bs[b_k][b_n8 + 6] = v1.z;
            Bs[b_k][b_n8 + 7] = v1.w;
        }
        __syncthreads();

#pragma unroll
        for (int k = 0; k < BK; ++k) {
            float a[8], b[8];
#pragma unroll
            for (int i = 0; i < 8; ++i) a[i] = As[k][ty + i * 16];
#pragma unroll
            for (int j = 0; j < 8; ++j) b[j] = Bs[k][tx + j * 16];
#pragma unroll
            for (int i = 0; i < 8; ++i)
#pragma unroll
                for (int j = 0; j < 8; ++j) acc[i][j] = fmaf(a[i], b[j], acc[i][j]);
        }
        __syncthreads();
    }

#pragma unroll
    for (int i = 0; i < 8; ++i) {
        int gm = bm + ty + i * 16;
        if (gm >= M) continue;
#pragma unroll
        for (int j = 0; j < 8; ++j) {
            int gn = bn + tx + j * 16;
            float* cp = C + (size_t)gm * N + gn;
            if (accumulate) *cp += acc[i][j];
            else *cp = acc[i][j];
        }
    }
}

// ---------------- launch ----------------
extern "C" void kernel_launch(void* const* d_in, const int* in_sizes, int n_in,
                              void* d_out, int out_size, void* d_ws, size_t ws_size,
                              hipStream_t stream) {
    const float* x       = (const float*)d_in[0];
    const int*   src     = (const int*)d_in[1];
    const int*   dst     = (const int*)d_in[2];
    const float* w_self1 = (const float*)d_in[3];
    const float* w_neigh1= (const float*)d_in[4];
    const float* b1      = (const float*)d_in[5];
    const float* w_self2 = (const float*)d_in[6];
    const float* w_neigh2= (const float*)d_in[7];
    const float* b2      = (const float*)d_in[8];
    float* out = (float*)d_out;

    // workspace carve-up (bytes), ~85 MB total
    char* ws = (char*)d_ws;
    size_t off = 0;
    auto alloc = [&](size_t bytes) {
        char* p = ws + off;
        off += (bytes + 255) & ~(size_t)255;
        return p;
    };
    int*   deg     = (int*)alloc(NREL * NN * 4);
    int*   offs    = (int*)alloc(NREL * NN * 4);
    int*   cursor  = (int*)alloc(NREL * NN * 4);
    int*   srclist = (int*)alloc((size_t)NREL * NE * 4);
    float* wsum1   = (float*)alloc(DIN * DHID * 4);
    float* bsum1   = (float*)alloc(DHID * 4);
    float* wsum2   = (float*)alloc(DHID * DOUT * 4);
    float* bsum2   = (float*)alloc(DOUT * 4);
    float* agg     = (float*)alloc((size_t)NN * DIN * 4);
    float* H       = (float*)alloc((size_t)NN * DHID * 4);

    // ---- CSR build (shared by both layers)
    hipMemsetAsync(deg, 0, NREL * NN * 4, stream);
    deg_kernel<<<(NREL * NE + 255) / 256, 256, 0, stream>>>(dst, deg);
    scan_kernel<<<NREL, 256, 0, stream>>>(deg, offs);
    hipMemcpyAsync(cursor, offs, NREL * NN * 4, hipMemcpyDeviceToDevice, stream);
    fill_kernel<<<(NREL * NE + 255) / 256, 256, 0, stream>>>(src, dst, cursor, srclist);

    // ---- summed self-weights / biases
    sum3_kernel<<<(DIN * DHID + 255) / 256, 256, 0, stream>>>(w_self1, wsum1, DIN * DHID);
    sum3_kernel<<<(DHID + 255) / 256, 256, 0, stream>>>(b1, bsum1, DHID);
    sum3_kernel<<<(DHID * DOUT + 255) / 256, 256, 0, stream>>>(w_self2, wsum2, DHID * DOUT);
    sum3_kernel<<<(DOUT + 255) / 256, 256, 0, stream>>>(b2, bsum2, DOUT);

    int gather_grid = (NN + 3) / 4;

    // ---- layer 1: H = relu(x@wsum1 + sum_r gathermean_r(x)@wn1_r + bsum1)
    init_bias_kernel<<<((NN * DHID) + 255) / 256, 256, 0, stream>>>(H, bsum1, NN * DHID, DHID);
    {
        dim3 grid((NN + BM - 1) / BM, DHID / BN);
        gemm_acc_kernel<<<grid, 256, 0, stream>>>(x, wsum1, H, NN, DIN, DHID, 1);
    }
    for (int r = 0; r < NREL; ++r) {
        gather_mean_kernel<<<gather_grid, 256, 0, stream>>>(
            x, offs + (size_t)r * NN, deg + (size_t)r * NN,
            srclist + (size_t)r * NE, agg, 0);
        dim3 grid((NN + BM - 1) / BM, DHID / BN);
        gemm_acc_kernel<<<grid, 256, 0, stream>>>(agg, w_neigh1 + (size_t)r * DIN * DHID,
                                                  H, NN, DIN, DHID, 1);
    }
    relu_kernel<<<((NN * DHID) + 255) / 256, 256, 0, stream>>>(H, NN * DHID);

    // ---- layer 2: out = H@wsum2 + sum_r gathermean_r(H@wn2_r) + bsum2
    init_bias_kernel<<<((NN * DOUT) + 255) / 256, 256, 0, stream>>>(out, bsum2, NN * DOUT, DOUT);
    {
        dim3 grid((NN + BM - 1) / BM, DOUT / BN);
        gemm_acc_kernel<<<grid, 256, 0, stream>>>(H, wsum2, out, NN, DHID, DOUT, 1);
    }
    for (int r = 0; r < NREL; ++r) {
        dim3 grid((NN + BM - 1) / BM, DOUT / BN);
        gemm_acc_kernel<<<grid, 256, 0, stream>>>(H, w_neigh2 + (size_t)r * DHID * DOUT,
                                                  agg, NN, DHID, DOUT, 0);
        gather_mean_kernel<<<gather_grid, 256, 0, stream>>>(
            agg, offs + (size_t)r * NN, deg + (size_t)r * NN,
            srclist + (size_t)r * NE, out, 1);
    }
}

// Round 3
// 519.412 us; speedup vs baseline: 11.1867x; 2.5104x over previous
//
#include <hip/hip_runtime.h>

#define NN 50000
#define NREL 3
#define NE 500000
#define DIN 128
#define DHID 256
#define DOUT 128

typedef unsigned int uint;
typedef unsigned short ushort;
typedef __attribute__((ext_vector_type(8))) short bf16x8;
typedef __attribute__((ext_vector_type(4))) float f32x4;

using gptr_t = const __attribute__((address_space(1))) unsigned int*;
using lptr_t = __attribute__((address_space(3))) unsigned int*;

__device__ __forceinline__ ushort f2bf(float f) {
    uint u = __float_as_uint(f);
    uint r = (u + 0x7fffu + ((u >> 16) & 1u)) >> 16;
    return (ushort)r;
}

// ---------------- CSR build ----------------
__global__ __launch_bounds__(256) void deg_kernel(const int* __restrict__ dst,
                                                  int* __restrict__ deg) {
    int t = blockIdx.x * 256 + threadIdx.x;
    if (t >= NREL * NE) return;
    int r = t / NE;
    atomicAdd(&deg[r * NN + dst[t]], 1);
}

#define SCH 1024
#define NCH 49   // ceil(NN / SCH)

__global__ __launch_bounds__(256) void scan_phase1(const int* __restrict__ deg,
                                                   int* __restrict__ csum) {
    int r = blockIdx.x / NCH, c = blockIdx.x % NCH;
    const int* d = deg + r * NN + c * SCH;
    int lim = NN - c * SCH;
    int s = 0;
    for (int i = threadIdx.x; i < SCH; i += 256)
        if (i < lim) s += d[i];
    __shared__ int red[256];
    red[threadIdx.x] = s;
    __syncthreads();
    for (int st = 128; st > 0; st >>= 1) {
        if (threadIdx.x < st) red[threadIdx.x] += red[threadIdx.x + st];
        __syncthreads();
    }
    if (threadIdx.x == 0) csum[r * NCH + c] = red[0];
}

__global__ __launch_bounds__(256) void scan_phase2(int* __restrict__ csum) {
    if (threadIdx.x < NREL) {
        int acc = 0;
        for (int c = 0; c < NCH; ++c) {
            int v = csum[threadIdx.x * NCH + c];
            csum[threadIdx.x * NCH + c] = acc;
            acc += v;
        }
    }
}

__global__ __launch_bounds__(256) void scan_phase3(const int* __restrict__ deg,
                                                   const int* __restrict__ csum,
                                                   int* __restrict__ offs) {
    int r = blockIdx.x / NCH, c = blockIdx.x % NCH;
    int base = c * SCH;
    int lim = NN - base;
    const int* d = deg + r * NN + base;
    int* o = offs + r * NN + base;
    int tid = threadIdx.x;
    int v[4];
    int s = 0;
#pragma unroll
    for (int j = 0; j < 4; ++j) {
        int i = tid * 4 + j;
        v[j] = (i < lim) ? d[i] : 0;
        s += v[j];
    }
    __shared__ int buf[256];
    buf[tid] = s;
    __syncthreads();
    for (int st = 1; st < 256; st <<= 1) {
        int t = (tid >= st) ? buf[tid - st] : 0;
        __syncthreads();
        buf[tid] += t;
        __syncthreads();
    }
    int ex = buf[tid] - s + csum[r * NCH + c];
#pragma unroll
    for (int j = 0; j < 4; ++j) {
        int i = tid * 4 + j;
        if (i < lim) o[i] = ex;
        ex += v[j];
    }
}

__global__ __launch_bounds__(256) void fill_kernel(const int* __restrict__ src,
                                                   const int* __restrict__ dst,
                                                   int* __restrict__ cursor,
                                                   int* __restrict__ srclist) {
    int t = blockIdx.x * 256 + threadIdx.x;
    if (t >= NREL * NE) return;
    int r = t / NE;
    int d = dst[t];
    int pos = atomicAdd(&cursor[r * NN + d], 1);
    srclist[(size_t)r * NE + pos] = src[t];
}

// ---------------- small helpers ----------------
__global__ __launch_bounds__(256) void sum3_kernel(const float* __restrict__ in,
                                                   float* __restrict__ out, int sz) {
    int t = blockIdx.x * 256 + threadIdx.x;
    if (t < sz) out[t] = in[t] + in[sz + t] + in[2 * sz + t];
}

__global__ __launch_bounds__(256) void f2bf_kernel(const float* __restrict__ in,
                                                   ushort* __restrict__ out, int n) {
    int t = blockIdx.x * 256 + threadIdx.x;
    if (t < n) out[t] = f2bf(in[t]);
}

// Bt1[n][k]: n in [0,256), k in [0,512). k-block 0 = sum_r w_self1, blocks 1-3 = w_neigh1[r]
__global__ __launch_bounds__(256) void pack_b1(const float* __restrict__ ws1,
                                               const float* __restrict__ wn1,
                                               ushort* __restrict__ Bt1) {
    int t = blockIdx.x * 256 + threadIdx.x;
    if (t >= 256 * 512) return;
    int n = t >> 9, k = t & 511;
    int b = k >> 7, kk = k & 127;
    float v;
    if (b == 0)
        v = ws1[kk * 256 + n] + ws1[128 * 256 + kk * 256 + n] + ws1[2 * 128 * 256 + kk * 256 + n];
    else
        v = wn1[(size_t)(b - 1) * 128 * 256 + kk * 256 + n];
    Bt1[t] = f2bf(v);
}

// Bt2[n][k]: n in [0,512), k in [0,256). n-block 0 = sum_r w_self2, blocks 1-3 = w_neigh2[r]
__global__ __launch_bounds__(256) void pack_b2(const float* __restrict__ ws2,
                                               const float* __restrict__ wn2,
                                               ushort* __restrict__ Bt2) {
    int t = blockIdx.x * 256 + threadIdx.x;
    if (t >= 512 * 256) return;
    int n = t >> 8, k = t & 255;
    int c = n >> 7, j = n & 127;
    float v;
    if (c == 0)
        v = ws2[k * 128 + j] + ws2[256 * 128 + k * 128 + j] + ws2[2 * 256 * 128 + k * 128 + j];
    else
        v = wn2[(size_t)(c - 1) * 256 * 128 + k * 128 + j];
    Bt2[t] = f2bf(v);
}

// ---------------- gather-mean: one wave per node, bf16 feature rows ----------------
template <int ACC>
__global__ __launch_bounds__(256) void gather_mean(
    const ushort* __restrict__ feat, const int* __restrict__ offs,
    const int* __restrict__ deg, const int* __restrict__ srclist,
    ushort* __restrict__ outb, float* __restrict__ outf) {
    int node = blockIdx.x * 4 + (threadIdx.x >> 6);
    if (node >= NN) return;
    int lane = threadIdx.x & 63;
    int beg = offs[node], d = deg[node];
    float ax = 0.f, ay = 0.f;
    for (int i = 0; i < d; i += 64) {
        int sid = (i + lane < d) ? srclist[beg + i + lane] : 0;
        int m = (d - i < 64) ? (d - i) : 64;
        for (int j = 0; j < m; ++j) {
            int s = __shfl(sid, j);
            uint v = *(const uint*)(feat + (size_t)s * 128 + lane * 2);
            ax += __uint_as_float(v << 16);
            ay += __uint_as_float(v & 0xffff0000u);
        }
    }
    float inv = 1.f / fmaxf((float)d, 1.f);
    ax *= inv;
    ay *= inv;
    if (ACC) {
        float* po = outf + (size_t)node * 128 + lane * 2;
        po[0] += ax;
        po[1] += ay;
    } else {
        uint pk = ((uint)f2bf(ax)) | (((uint)f2bf(ay)) << 16);
        *(uint*)(outb + (size_t)node * 128 + lane * 2) = pk;
    }
}

// ---------------- bf16 MFMA GEMM ----------------
// 128x128 tile, BK=32, 4 waves (2x2), each wave 64x64 via 4x4 frags of 16x16x32.
// LAYER 1: A = 4 buffers [M][128] (k-blocked), C = H bf16 [M][256], bias+relu.
// LAYER 2: A = H [M][256], C per blockIdx.y: 0 -> out fp32 [M][128] (+bias), 1..3 -> Y bf16 [M][128].
template <int LAYER>
__global__ __launch_bounds__(256) void gemm_mfma(
    const ushort* __restrict__ A0, const ushort* __restrict__ A1,
    const ushort* __restrict__ A2, const ushort* __restrict__ A3,
    const ushort* __restrict__ Bt, const float* __restrict__ bias,
    ushort* __restrict__ HO, float* __restrict__ CO,
    ushort* __restrict__ Y1, ushort* __restrict__ Y2, ushort* __restrict__ Y3) {
    constexpr int KTOT = (LAYER == 1) ? 512 : 256;
    constexpr int ASTRIDE = (LAYER == 1) ? 128 : 256;
    __shared__ __align__(16) ushort As[128 * 32];
    __shared__ __align__(16) ushort Bs[128 * 32];

    const int tid = threadIdx.x, lane = tid & 63, w = tid >> 6;
    const int wr = w >> 1, wc = w & 1;
    const int bm = blockIdx.x * 128;
    const int bn = blockIdx.y * 128;

    f32x4 acc[4][4];
#pragma unroll
    for (int m = 0; m < 4; ++m)
#pragma unroll
        for (int n = 0; n < 4; ++n) acc[m][n] = (f32x4){0.f, 0.f, 0.f, 0.f};

    const int arow = lane >> 2;       // row within 16-row chunk
    const int akq = (lane & 3) * 8;   // ushort offset within row

    for (int k0 = 0; k0 < KTOT; k0 += 32) {
        const ushort* Ab = A0;
        int koff = k0;
        if (LAYER == 1) {
            int b = k0 >> 7;
            Ab = (b == 0) ? A0 : (b == 1) ? A1 : (b == 2) ? A2 : A3;
            koff = k0 & 127;
        }
#pragma unroll
        for (int i = 0; i < 2; ++i) {
            int c = w + i * 4;
            const ushort* srcA = Ab + (size_t)(bm + c * 16 + arow) * ASTRIDE + koff + akq;
            __builtin_amdgcn_global_load_lds((gptr_t)srcA, (lptr_t)(As + c * 512), 16, 0, 0);
            const ushort* srcB = Bt + (size_t)(bn + c * 16 + arow) * KTOT + k0 + akq;
            __builtin_amdgcn_global_load_lds((gptr_t)srcB, (lptr_t)(Bs + c * 512), 16, 0, 0);
        }
        __syncthreads();

        const int r = lane & 15, g = lane >> 4;
        bf16x8 af[4], bg[4];
#pragma unroll
        for (int m = 0; m < 4; ++m)
            af[m] = *(const bf16x8*)&As[(wr * 64 + m * 16 + r) * 32 + g * 8];
#pragma unroll
        for (int n = 0; n < 4; ++n)
            bg[n] = *(const bf16x8*)&Bs[(wc * 64 + n * 16 + r) * 32 + g * 8];
#pragma unroll
        for (int m = 0; m < 4; ++m)
#pragma unroll
            for (int n = 0; n < 4; ++n)
                acc[m][n] = __builtin_amdgcn_mfma_f32_16x16x32_bf16(af[m], bg[n], acc[m][n], 0, 0, 0);
        __syncthreads();
    }

    // epilogue: C row = bm + wr*64 + m*16 + g*4 + v ; col-in-tile = wc*64 + n*16 + r
    const int r = lane & 15, g = lane >> 4;
    if (LAYER == 1) {
#pragma unroll
        for (int m = 0; m < 4; ++m)
#pragma unroll
            for (int v = 0; v < 4; ++v) {
                int gm = bm + wr * 64 + m * 16 + g * 4 + v;
                if (gm >= NN) continue;
#pragma unroll
                for (int n = 0; n < 4; ++n) {
                    int gn = bn + wc * 64 + n * 16 + r;
                    float f = acc[m][n][v] + bias[gn];
                    f = fmaxf(f, 0.f);
                    HO[(size_t)gm * 256 + gn] = f2bf(f);
                }
            }
    } else {
        if (blockIdx.y == 0) {
#pragma unroll
            for (int m = 0; m < 4; ++m)
#pragma unroll
                for (int v = 0; v < 4; ++v) {
                    int gm = bm + wr * 64 + m * 16 + g * 4 + v;
                    if (gm >= NN) continue;
#pragma unroll
                    for (int n = 0; n < 4; ++n) {
                        int gn = wc * 64 + n * 16 + r;
                        CO[(size_t)gm * 128 + gn] = acc[m][n][v] + bias[gn];
                    }
                }
        } else {
            ushort* Y = (blockIdx.y == 1) ? Y1 : (blockIdx.y == 2) ? Y2 : Y3;
#pragma unroll
            for (int m = 0; m < 4; ++m)
#pragma unroll
                for (int v = 0; v < 4; ++v) {
                    int gm = bm + wr * 64 + m * 16 + g * 4 + v;
                    if (gm >= NN) continue;
#pragma unroll
                    for (int n = 0; n < 4; ++n) {
                        int gn = wc * 64 + n * 16 + r;
                        Y[(size_t)gm * 128 + gn] = f2bf(acc[m][n][v]);
                    }
                }
        }
    }
}

// ---------------- launch ----------------
extern "C" void kernel_launch(void* const* d_in, const int* in_sizes, int n_in,
                              void* d_out, int out_size, void* d_ws, size_t ws_size,
                              hipStream_t stream) {
    const float* x        = (const float*)d_in[0];
    const int*   src      = (const int*)d_in[1];
    const int*   dst      = (const int*)d_in[2];
    const float* w_self1  = (const float*)d_in[3];
    const float* w_neigh1 = (const float*)d_in[4];
    const float* b1       = (const float*)d_in[5];
    const float* w_self2  = (const float*)d_in[6];
    const float* w_neigh2 = (const float*)d_in[7];
    const float* b2       = (const float*)d_in[8];
    float* out = (float*)d_out;

    char* ws = (char*)d_ws;
    size_t off = 0;
    auto alloc = [&](size_t bytes) {
        char* p = ws + off;
        off += (bytes + 255) & ~(size_t)255;
        return p;
    };
    int*    deg     = (int*)alloc(NREL * NN * 4);
    int*    offs    = (int*)alloc(NREL * NN * 4);
    int*    cursor  = (int*)alloc(NREL * NN * 4);
    int*    csum    = (int*)alloc(NREL * NCH * 4);
    int*    srclist = (int*)alloc((size_t)NREL * NE * 4);
    float*  bsum1   = (float*)alloc(DHID * 4);
    float*  bsum2   = (float*)alloc(DOUT * 4);
    ushort* Bt1     = (ushort*)alloc((size_t)DHID * 512 * 2);      // [256][512]
    ushort* Bt2     = (ushort*)alloc((size_t)512 * DHID * 2);      // [512][256]
    ushort* xb      = (ushort*)alloc((size_t)NN * DIN * 2);
    ushort* aggb    = (ushort*)alloc((size_t)NREL * NN * DIN * 2); // agg / reused as Y
    ushort* Hb      = (ushort*)alloc((size_t)NN * DHID * 2);
    (void)alloc(65536); // guard for OOB tile over-reads on the last M-block

    // ---- CSR build
    hipMemsetAsync(deg, 0, NREL * NN * 4, stream);
    deg_kernel<<<(NREL * NE + 255) / 256, 256, 0, stream>>>(dst, deg);
    scan_phase1<<<NREL * NCH, 256, 0, stream>>>(deg, csum);
    scan_phase2<<<1, 256, 0, stream>>>(csum);
    scan_phase3<<<NREL * NCH, 256, 0, stream>>>(deg, csum, offs);
    hipMemcpyAsync(cursor, offs, NREL * NN * 4, hipMemcpyDeviceToDevice, stream);
    fill_kernel<<<(NREL * NE + 255) / 256, 256, 0, stream>>>(src, dst, cursor, srclist);

    // ---- packs / conversions
    f2bf_kernel<<<(NN * DIN + 255) / 256, 256, 0, stream>>>(x, xb, NN * DIN);
    sum3_kernel<<<1, 256, 0, stream>>>(b1, bsum1, DHID);
    sum3_kernel<<<1, 256, 0, stream>>>(b2, bsum2, DOUT);
    pack_b1<<<(256 * 512 + 255) / 256, 256, 0, stream>>>(w_self1, w_neigh1, Bt1);
    pack_b2<<<(512 * 256 + 255) / 256, 256, 0, stream>>>(w_self2, w_neigh2, Bt2);

    int ggrid = (NN + 3) / 4;

    // ---- layer 1 gathers: agg_r = mean_r(x)  (bf16 in, bf16 out)
    for (int r = 0; r < NREL; ++r) {
        gather_mean<0><<<ggrid, 256, 0, stream>>>(
            xb, offs + (size_t)r * NN, deg + (size_t)r * NN,
            srclist + (size_t)r * NE, aggb + (size_t)r * NN * DIN, nullptr);
    }
    // ---- layer 1 fused GEMM: H = relu([x|agg0|agg1|agg2] @ Bt1^T + bsum1)
    {
        dim3 grid((NN + 127) / 128, DHID / 128);
        gemm_mfma<1><<<grid, 256, 0, stream>>>(
            xb, aggb, aggb + (size_t)NN * DIN, aggb + (size_t)2 * NN * DIN,
            Bt1, bsum1, Hb, nullptr, nullptr, nullptr, nullptr);
    }
    // ---- layer 2 fused GEMM: [out | y0 | y1 | y2] = H @ Bt2^T (+bias on out)
    {
        dim3 grid((NN + 127) / 128, 4);
        gemm_mfma<2><<<grid, 256, 0, stream>>>(
            Hb, nullptr, nullptr, nullptr, Bt2, bsum2,
            nullptr, out, aggb, aggb + (size_t)NN * DIN, aggb + (size_t)2 * NN * DIN);
    }
    // ---- layer 2 gathers: out += mean_r(y_r)
    for (int r = 0; r < NREL; ++r) {
        gather_mean<1><<<ggrid, 256, 0, stream>>>(
            aggb + (size_t)r * NN * DIN, offs + (size_t)r * NN, deg + (size_t)r * NN,
            srclist + (size_t)r * NE, nullptr, out);
    }
}

// Round 4
// 262.619 us; speedup vs baseline: 22.1251x; 1.9778x over previous
//
#include <hip/hip_runtime.h>

#define NN 50000
#define NREL 3
#define NE 500000
#define DIN 128
#define DHID 256
#define DOUT 128

#define NBUK 98          // ceil(50000/512) dst-buckets of 512 nodes
#define CAP 8192         // pair capacity per bucket (expected ~5100, sigma ~71)
#define EPB 2048         // edges per pass-A block
#define NCHK ((NE + EPB - 1) / EPB)   // 245

typedef unsigned int uint;
typedef unsigned short ushort;
typedef __attribute__((ext_vector_type(8))) short bf16x8;
typedef __attribute__((ext_vector_type(4))) float f32x4;

using gptr_t = const __attribute__((address_space(1))) unsigned int*;
using lptr_t = __attribute__((address_space(3))) unsigned int*;

__device__ __forceinline__ ushort f2bf(float f) {
    uint u = __float_as_uint(f);
    uint r = (u + 0x7fffu + ((u >> 16) & 1u)) >> 16;
    return (ushort)r;
}
__device__ __forceinline__ float bflo(uint u) { return __uint_as_float(u << 16); }
__device__ __forceinline__ float bfhi(uint u) { return __uint_as_float(u & 0xffff0000u); }

// ---------------- bucketed CSR build ----------------
// Pass A: bucket edges by dst>>9, packed (src<<9)|dst_local into per-bucket regions.
__global__ __launch_bounds__(256) void pass_a(const int* __restrict__ src,
                                              const int* __restrict__ dst,
                                              int* __restrict__ bcursor,
                                              uint* __restrict__ pairs) {
    int r = blockIdx.x / NCHK;
    int chunk = blockIdx.x % NCHK;
    int e0 = chunk * EPB;
    int nedge = min(EPB, NE - e0);
    const int* S = src + (size_t)r * NE + e0;
    const int* D = dst + (size_t)r * NE + e0;
    __shared__ int cnt[NBUK], base[NBUK], cur[NBUK];
    int tid = threadIdx.x;
    if (tid < NBUK) { cnt[tid] = 0; cur[tid] = 0; }
    __syncthreads();
    uint pk[8];
    int bk[8];
    bool val[8];
#pragma unroll
    for (int j = 0; j < 8; ++j) {
        int e = j * 256 + tid;
        val[j] = e < nedge;
        int d = val[j] ? D[e] : 0;
        int s = val[j] ? S[e] : 0;
        bk[j] = d >> 9;
        pk[j] = ((uint)s << 9) | (uint)(d & 511);
        if (val[j]) atomicAdd(&cnt[bk[j]], 1);
    }
    __syncthreads();
    if (tid < NBUK) base[tid] = atomicAdd(&bcursor[r * NBUK + tid], cnt[tid]);
    __syncthreads();
#pragma unroll
    for (int j = 0; j < 8; ++j) {
        if (val[j]) {
            int slot = base[bk[j]] + atomicAdd(&cur[bk[j]], 1);
            if (slot < CAP) pairs[(size_t)(r * NBUK + bk[j]) * CAP + slot] = pk[j];
        }
    }
}

// exclusive scan of the 294 bucket counts (one block)
__global__ __launch_bounds__(256) void bucket_scan(const int* __restrict__ bcnt,
                                                   int* __restrict__ boffs) {
    __shared__ int sc[256];
    int tid = threadIdx.x;
    int i0 = 2 * tid, i1 = 2 * tid + 1;
    int v0 = (i0 < NREL * NBUK) ? bcnt[i0] : 0;
    int v1 = (i1 < NREL * NBUK) ? bcnt[i1] : 0;
    int s = v0 + v1;
    sc[tid] = s;
    __syncthreads();
    for (int st = 1; st < 256; st <<= 1) {
        int t = (tid >= st) ? sc[tid - st] : 0;
        __syncthreads();
        sc[tid] += t;
        __syncthreads();
    }
    int excl = sc[tid] - s;
    if (i0 < NREL * NBUK) boffs[i0] = excl;
    if (i1 < NREL * NBUK) boffs[i1] = excl + v0;
}

// Pass B: per bucket, node histogram + scan in LDS, scatter srcs, emit deg/offs.
__global__ __launch_bounds__(256) void pass_b(const uint* __restrict__ pairs,
                                              const int* __restrict__ bcnt,
                                              const int* __restrict__ boffs,
                                              int* __restrict__ srclist,
                                              int* __restrict__ deg,
                                              int* __restrict__ offs) {
    int blk = blockIdx.x;
    int b = blk % NBUK;
    int r = blk / NBUK;
    int node_base = b * 512;
    int count = min(bcnt[blk], CAP);
    int obase = boffs[blk];
    const uint* pp = pairs + (size_t)blk * CAP;
    __shared__ int hist[512];
    __shared__ int cur[512];
    __shared__ int sc[256];
    int tid = threadIdx.x;
    hist[tid] = 0;
    hist[tid + 256] = 0;
    __syncthreads();
    for (int i = tid; i < count; i += 256) atomicAdd(&hist[pp[i] & 511], 1);
    __syncthreads();
    int v0 = hist[2 * tid], v1 = hist[2 * tid + 1];
    int s = v0 + v1;
    sc[tid] = s;
    __syncthreads();
    for (int st = 1; st < 256; st <<= 1) {
        int t = (tid >= st) ? sc[tid - st] : 0;
        __syncthreads();
        sc[tid] += t;
        __syncthreads();
    }
    int excl = sc[tid] - s;
    int c0 = obase + excl;
    int c1 = c0 + v0;
    cur[2 * tid] = c0;
    cur[2 * tid + 1] = c1;
    int n0 = node_base + 2 * tid;
    if (n0 < NN)     { deg[r * NN + n0] = v0;     offs[r * NN + n0] = c0; }
    if (n0 + 1 < NN) { deg[r * NN + n0 + 1] = v1; offs[r * NN + n0 + 1] = c1; }
    __syncthreads();
    for (int i = tid; i < count; i += 256) {
        uint p = pp[i];
        int pos = atomicAdd(&cur[p & 511], 1);
        srclist[pos] = (int)(p >> 9);
    }
}

// ---------------- small helpers ----------------
__global__ __launch_bounds__(256) void sum3_kernel(const float* __restrict__ in,
                                                   float* __restrict__ out, int sz) {
    int t = blockIdx.x * 256 + threadIdx.x;
    if (t < sz) out[t] = in[t] + in[sz + t] + in[2 * sz + t];
}

// fp32 -> bf16, 4 at a time
__global__ __launch_bounds__(256) void f2bf_vec_kernel(const float* __restrict__ in,
                                                       ushort* __restrict__ out, int n4) {
    int t = blockIdx.x * 256 + threadIdx.x;
    if (t >= n4) return;
    float4 v = *(const float4*)(in + (size_t)t * 4);
    uint2 p;
    p.x = (uint)f2bf(v.x) | ((uint)f2bf(v.y) << 16);
    p.y = (uint)f2bf(v.z) | ((uint)f2bf(v.w) << 16);
    *(uint2*)(out + (size_t)t * 4) = p;
}

__global__ __launch_bounds__(256) void pack_b1(const float* __restrict__ ws1,
                                               const float* __restrict__ wn1,
                                               ushort* __restrict__ Bt1) {
    int t = blockIdx.x * 256 + threadIdx.x;
    if (t >= 256 * 512) return;
    int n = t >> 9, k = t & 511;
    int b = k >> 7, kk = k & 127;
    float v;
    if (b == 0)
        v = ws1[kk * 256 + n] + ws1[128 * 256 + kk * 256 + n] + ws1[2 * 128 * 256 + kk * 256 + n];
    else
        v = wn1[(size_t)(b - 1) * 128 * 256 + kk * 256 + n];
    Bt1[t] = f2bf(v);
}

__global__ __launch_bounds__(256) void pack_b2(const float* __restrict__ ws2,
                                               const float* __restrict__ wn2,
                                               ushort* __restrict__ Bt2) {
    int t = blockIdx.x * 256 + threadIdx.x;
    if (t >= 512 * 256) return;
    int n = t >> 8, k = t & 255;
    int c = n >> 7, j = n & 127;
    float v;
    if (c == 0)
        v = ws2[k * 128 + j] + ws2[256 * 128 + k * 128 + j] + ws2[2 * 256 * 128 + k * 128 + j];
    else
        v = wn2[(size_t)(c - 1) * 256 * 128 + k * 128 + j];
    Bt2[t] = f2bf(v);
}

// ---------------- merged gather-mean: one wave per node, 3 relations ----------------
// lane = g*16 + c: g = neighbor sub-row 0..3, c = 16B column chunk 0..15.
// PHASE 0: write bf16 agg rows per relation. PHASE 1: out += sum_r mean_r (fp32 RMW).
template <int PHASE>
__global__ __launch_bounds__(256) void gather3(
    const ushort* __restrict__ f0, const ushort* __restrict__ f1,
    const ushort* __restrict__ f2, const int* __restrict__ offs,
    const int* __restrict__ deg, const int* __restrict__ srclist,
    ushort* __restrict__ ob, float* __restrict__ of) {
    int node = blockIdx.x * 4 + (threadIdx.x >> 6);
    if (node >= NN) return;
    int lane = threadIdx.x & 63;
    int g = lane >> 4, c = lane & 15;
    float msum[8];
#pragma unroll
    for (int k = 0; k < 8; ++k) msum[k] = 0.f;

    for (int r = 0; r < NREL; ++r) {
        const ushort* feat = (r == 0) ? f0 : (r == 1) ? f1 : f2;
        int beg = offs[r * NN + node];
        int d = deg[r * NN + node];
        float acc[8];
#pragma unroll
        for (int k = 0; k < 8; ++k) acc[k] = 0.f;

        for (int i = 0; i < d; i += 64) {
            int sid_l = (i + lane < d) ? srclist[beg + i + lane] : 0;
            int m = (d - i < 64) ? (d - i) : 64;
            for (int j0 = 0; j0 < m; j0 += 4) {
                int jj = j0 + g;
                int sid = __shfl(sid_l, (jj < m) ? jj : 0);
                if (jj < m) {
                    uint4 v = *(const uint4*)(feat + (size_t)sid * 128 + c * 8);
                    acc[0] += bflo(v.x); acc[1] += bfhi(v.x);
                    acc[2] += bflo(v.y); acc[3] += bfhi(v.y);
                    acc[4] += bflo(v.z); acc[5] += bfhi(v.z);
                    acc[6] += bflo(v.w); acc[7] += bfhi(v.w);
                }
            }
        }
        // reduce the 4 g-groups (lanes c, c+16, c+32, c+48)
#pragma unroll
        for (int k = 0; k < 8; ++k) {
            acc[k] += __shfl_xor(acc[k], 16);
            acc[k] += __shfl_xor(acc[k], 32);
        }
        float inv = 1.f / fmaxf((float)d, 1.f);
        if (PHASE == 0) {
            if (g == 0) {
                uint4 pk;
                pk.x = (uint)f2bf(acc[0] * inv) | ((uint)f2bf(acc[1] * inv) << 16);
                pk.y = (uint)f2bf(acc[2] * inv) | ((uint)f2bf(acc[3] * inv) << 16);
                pk.z = (uint)f2bf(acc[4] * inv) | ((uint)f2bf(acc[5] * inv) << 16);
                pk.w = (uint)f2bf(acc[6] * inv) | ((uint)f2bf(acc[7] * inv) << 16);
                *(uint4*)(ob + (size_t)r * NN * DIN + (size_t)node * 128 + c * 8) = pk;
            }
        } else {
#pragma unroll
            for (int k = 0; k < 8; ++k) msum[k] += acc[k] * inv;
        }
    }
    if (PHASE == 1 && g == 0) {
        float* po = of + (size_t)node * 128 + c * 8;
        float4 a = *(float4*)po;
        float4 b = *(float4*)(po + 4);
        a.x += msum[0]; a.y += msum[1]; a.z += msum[2]; a.w += msum[3];
        b.x += msum[4]; b.y += msum[5]; b.z += msum[6]; b.w += msum[7];
        *(float4*)po = a;
        *(float4*)(po + 4) = b;
    }
}

// ---------------- bf16 MFMA GEMM (unchanged from round 3) ----------------
template <int LAYER>
__global__ __launch_bounds__(256) void gemm_mfma(
    const ushort* __restrict__ A0, const ushort* __restrict__ A1,
    const ushort* __restrict__ A2, const ushort* __restrict__ A3,
    const ushort* __restrict__ Bt, const float* __restrict__ bias,
    ushort* __restrict__ HO, float* __restrict__ CO,
    ushort* __restrict__ Y1, ushort* __restrict__ Y2, ushort* __restrict__ Y3) {
    constexpr int KTOT = (LAYER == 1) ? 512 : 256;
    constexpr int ASTRIDE = (LAYER == 1) ? 128 : 256;
    __shared__ __align__(16) ushort As[128 * 32];
    __shared__ __align__(16) ushort Bs[128 * 32];

    const int tid = threadIdx.x, lane = tid & 63, w = tid >> 6;
    const int wr = w >> 1, wc = w & 1;
    const int bm = blockIdx.x * 128;
    const int bn = blockIdx.y * 128;

    f32x4 acc[4][4];
#pragma unroll
    for (int m = 0; m < 4; ++m)
#pragma unroll
        for (int n = 0; n < 4; ++n) acc[m][n] = (f32x4){0.f, 0.f, 0.f, 0.f};

    const int arow = lane >> 2;
    const int akq = (lane & 3) * 8;

    for (int k0 = 0; k0 < KTOT; k0 += 32) {
        const ushort* Ab = A0;
        int koff = k0;
        if (LAYER == 1) {
            int b = k0 >> 7;
            Ab = (b == 0) ? A0 : (b == 1) ? A1 : (b == 2) ? A2 : A3;
            koff = k0 & 127;
        }
#pragma unroll
        for (int i = 0; i < 2; ++i) {
            int c = w + i * 4;
            const ushort* srcA = Ab + (size_t)(bm + c * 16 + arow) * ASTRIDE + koff + akq;
            __builtin_amdgcn_global_load_lds((gptr_t)srcA, (lptr_t)(As + c * 512), 16, 0, 0);
            const ushort* srcB = Bt + (size_t)(bn + c * 16 + arow) * KTOT + k0 + akq;
            __builtin_amdgcn_global_load_lds((gptr_t)srcB, (lptr_t)(Bs + c * 512), 16, 0, 0);
        }
        __syncthreads();

        const int r = lane & 15, g = lane >> 4;
        bf16x8 af[4], bg[4];
#pragma unroll
        for (int m = 0; m < 4; ++m)
            af[m] = *(const bf16x8*)&As[(wr * 64 + m * 16 + r) * 32 + g * 8];
#pragma unroll
        for (int n = 0; n < 4; ++n)
            bg[n] = *(const bf16x8*)&Bs[(wc * 64 + n * 16 + r) * 32 + g * 8];
#pragma unroll
        for (int m = 0; m < 4; ++m)
#pragma unroll
            for (int n = 0; n < 4; ++n)
                acc[m][n] = __builtin_amdgcn_mfma_f32_16x16x32_bf16(af[m], bg[n], acc[m][n], 0, 0, 0);
        __syncthreads();
    }

    const int r = lane & 15, g = lane >> 4;
    if (LAYER == 1) {
#pragma unroll
        for (int m = 0; m < 4; ++m)
#pragma unroll
            for (int v = 0; v < 4; ++v) {
                int gm = bm + wr * 64 + m * 16 + g * 4 + v;
                if (gm >= NN) continue;
#pragma unroll
                for (int n = 0; n < 4; ++n) {
                    int gn = bn + wc * 64 + n * 16 + r;
                    float f = acc[m][n][v] + bias[gn];
                    f = fmaxf(f, 0.f);
                    HO[(size_t)gm * 256 + gn] = f2bf(f);
                }
            }
    } else {
        if (blockIdx.y == 0) {
#pragma unroll
            for (int m = 0; m < 4; ++m)
#pragma unroll
                for (int v = 0; v < 4; ++v) {
                    int gm = bm + wr * 64 + m * 16 + g * 4 + v;
                    if (gm >= NN) continue;
#pragma unroll
                    for (int n = 0; n < 4; ++n) {
                        int gn = wc * 64 + n * 16 + r;
                        CO[(size_t)gm * 128 + gn] = acc[m][n][v] + bias[gn];
                    }
                }
        } else {
            ushort* Y = (blockIdx.y == 1) ? Y1 : (blockIdx.y == 2) ? Y2 : Y3;
#pragma unroll
            for (int m = 0; m < 4; ++m)
#pragma unroll
                for (int v = 0; v < 4; ++v) {
                    int gm = bm + wr * 64 + m * 16 + g * 4 + v;
                    if (gm >= NN) continue;
#pragma unroll
                    for (int n = 0; n < 4; ++n) {
                        int gn = wc * 64 + n * 16 + r;
                        Y[(size_t)gm * 128 + gn] = f2bf(acc[m][n][v]);
                    }
                }
        }
    }
}

// ---------------- launch ----------------
extern "C" void kernel_launch(void* const* d_in, const int* in_sizes, int n_in,
                              void* d_out, int out_size, void* d_ws, size_t ws_size,
                              hipStream_t stream) {
    const float* x        = (const float*)d_in[0];
    const int*   src      = (const int*)d_in[1];
    const int*   dst      = (const int*)d_in[2];
    const float* w_self1  = (const float*)d_in[3];
    const float* w_neigh1 = (const float*)d_in[4];
    const float* b1       = (const float*)d_in[5];
    const float* w_self2  = (const float*)d_in[6];
    const float* w_neigh2 = (const float*)d_in[7];
    const float* b2       = (const float*)d_in[8];
    float* out = (float*)d_out;

    char* ws = (char*)d_ws;
    size_t off = 0;
    auto alloc = [&](size_t bytes) {
        char* p = ws + off;
        off += (bytes + 255) & ~(size_t)255;
        return p;
    };
    int*    bcursor = (int*)alloc(NREL * NBUK * 4);
    int*    boffs   = (int*)alloc(NREL * NBUK * 4);
    int*    deg     = (int*)alloc(NREL * NN * 4);
    int*    offs    = (int*)alloc(NREL * NN * 4);
    int*    srclist = (int*)alloc((size_t)NREL * NE * 4);
    float*  bsum1   = (float*)alloc(DHID * 4);
    float*  bsum2   = (float*)alloc(DOUT * 4);
    ushort* Bt1     = (ushort*)alloc((size_t)DHID * 512 * 2);
    ushort* Bt2     = (ushort*)alloc((size_t)512 * DHID * 2);
    ushort* xb      = (ushort*)alloc((size_t)NN * DIN * 2);
    ushort* aggb    = (ushort*)alloc((size_t)NREL * NN * DIN * 2);
    ushort* Hb      = (ushort*)alloc((size_t)NN * DHID * 2);
    (void)alloc(65536); // guard for GEMM tile over-reads past last M-block
    // pairs buffer aliases Hb: consumed by pass_b before layer-1 GEMM writes Hb.
    uint* pairs = (uint*)Hb;   // needs 3*98*8192*4 = 9.6 MB < 25.6 MB

    // ---- CSR build (bucketed counting sort)
    hipMemsetAsync(bcursor, 0, NREL * NBUK * 4, stream);
    pass_a<<<NREL * NCHK, 256, 0, stream>>>(src, dst, bcursor, pairs);
    bucket_scan<<<1, 256, 0, stream>>>(bcursor, boffs);
    pass_b<<<NREL * NBUK, 256, 0, stream>>>(pairs, bcursor, boffs, srclist, deg, offs);

    // ---- packs / conversions
    f2bf_vec_kernel<<<(NN * DIN / 4 + 255) / 256, 256, 0, stream>>>(x, xb, NN * DIN / 4);
    sum3_kernel<<<1, 256, 0, stream>>>(b1, bsum1, DHID);
    sum3_kernel<<<1, 256, 0, stream>>>(b2, bsum2, DOUT);
    pack_b1<<<(256 * 512 + 255) / 256, 256, 0, stream>>>(w_self1, w_neigh1, Bt1);
    pack_b2<<<(512 * 256 + 255) / 256, 256, 0, stream>>>(w_self2, w_neigh2, Bt2);

    int ggrid = (NN + 3) / 4;

    // ---- layer 1: agg_r = mean_r(x) for all 3 relations in one kernel
    gather3<0><<<ggrid, 256, 0, stream>>>(xb, xb, xb, offs, deg, srclist, aggb, nullptr);
    // ---- layer 1 fused GEMM: H = relu([x|agg0|agg1|agg2] @ Bt1^T + bsum1)
    {
        dim3 grid((NN + 127) / 128, DHID / 128);
        gemm_mfma<1><<<grid, 256, 0, stream>>>(
            xb, aggb, aggb + (size_t)NN * DIN, aggb + (size_t)2 * NN * DIN,
            Bt1, bsum1, Hb, nullptr, nullptr, nullptr, nullptr);
    }
    // ---- layer 2 fused GEMM: [out | y0 | y1 | y2] = H @ Bt2^T (+bias on out)
    {
        dim3 grid((NN + 127) / 128, 4);
        gemm_mfma<2><<<grid, 256, 0, stream>>>(
            Hb, nullptr, nullptr, nullptr, Bt2, bsum2,
            nullptr, out, aggb, aggb + (size_t)NN * DIN, aggb + (size_t)2 * NN * DIN);
    }
    // ---- layer 2: out += sum_r mean_r(y_r), one RMW of out
    gather3<1><<<ggrid, 256, 0, stream>>>(
        aggb, aggb + (size_t)NN * DIN, aggb + (size_t)2 * NN * DIN,
        offs, deg, srclist, nullptr, out);
}

// Round 5
// 243.726 us; speedup vs baseline: 23.8402x; 1.0775x over previous
//
#include <hip/hip_runtime.h>

#define NN 50000
#define NREL 3
#define NE 500000
#define DIN 128
#define DHID 256
#define DOUT 128

#define NBUK 98          // ceil(50000/512) dst-buckets of 512 nodes
#define CAP 8192         // pair capacity per bucket (expected ~5100, sigma ~71)
#define EPB 2048         // edges per pass-A block
#define NCHK ((NE + EPB - 1) / EPB)   // 245

typedef unsigned int uint;
typedef unsigned short ushort;
typedef __attribute__((ext_vector_type(8))) short bf16x8;
typedef __attribute__((ext_vector_type(4))) float f32x4;

using gptr_t = const __attribute__((address_space(1))) unsigned int*;
using lptr_t = __attribute__((address_space(3))) unsigned int*;

__device__ __forceinline__ ushort f2bf(float f) {
    uint u = __float_as_uint(f);
    uint r = (u + 0x7fffu + ((u >> 16) & 1u)) >> 16;
    return (ushort)r;
}
__device__ __forceinline__ void acc2(float2& a, uint u) {
    a.x += __uint_as_float(u << 16);
    a.y += __uint_as_float(u & 0xffff0000u);
}

// ---------------- bucketed CSR build ----------------
__global__ __launch_bounds__(256) void pass_a(const int* __restrict__ src,
                                              const int* __restrict__ dst,
                                              int* __restrict__ bcursor,
                                              uint* __restrict__ pairs) {
    int r = blockIdx.x / NCHK;
    int chunk = blockIdx.x % NCHK;
    int e0 = chunk * EPB;
    int nedge = min(EPB, NE - e0);
    const int* S = src + (size_t)r * NE + e0;
    const int* D = dst + (size_t)r * NE + e0;
    __shared__ int cnt[NBUK], base[NBUK], cur[NBUK];
    int tid = threadIdx.x;
    if (tid < NBUK) { cnt[tid] = 0; cur[tid] = 0; }
    __syncthreads();
    uint pk[8];
    int bk[8];
    bool val[8];
#pragma unroll
    for (int j = 0; j < 8; ++j) {
        int e = j * 256 + tid;
        val[j] = e < nedge;
        int d = val[j] ? D[e] : 0;
        int s = val[j] ? S[e] : 0;
        bk[j] = d >> 9;
        pk[j] = ((uint)s << 9) | (uint)(d & 511);
        if (val[j]) atomicAdd(&cnt[bk[j]], 1);
    }
    __syncthreads();
    if (tid < NBUK) base[tid] = atomicAdd(&bcursor[r * NBUK + tid], cnt[tid]);
    __syncthreads();
#pragma unroll
    for (int j = 0; j < 8; ++j) {
        if (val[j]) {
            int slot = base[bk[j]] + atomicAdd(&cur[bk[j]], 1);
            if (slot < CAP) pairs[(size_t)(r * NBUK + bk[j]) * CAP + slot] = pk[j];
        }
    }
}

// Per bucket: node histogram + scan in LDS, scatter srcs into the bucket's
// OWN srclist region at blk*CAP (no global packing needed), emit deg/offs.
__global__ __launch_bounds__(256) void pass_b(const uint* __restrict__ pairs,
                                              const int* __restrict__ bcnt,
                                              int* __restrict__ srclist,
                                              int* __restrict__ deg,
                                              int* __restrict__ offs) {
    int blk = blockIdx.x;
    int b = blk % NBUK;
    int r = blk / NBUK;
    int node_base = b * 512;
    int count = min(bcnt[blk], CAP);
    int obase = blk * CAP;
    const uint* pp = pairs + (size_t)blk * CAP;
    __shared__ int hist[512];
    __shared__ int cur[512];
    __shared__ int sc[256];
    int tid = threadIdx.x;
    hist[tid] = 0;
    hist[tid + 256] = 0;
    __syncthreads();
    for (int i = tid; i < count; i += 256) atomicAdd(&hist[pp[i] & 511], 1);
    __syncthreads();
    int v0 = hist[2 * tid], v1 = hist[2 * tid + 1];
    int s = v0 + v1;
    sc[tid] = s;
    __syncthreads();
    for (int st = 1; st < 256; st <<= 1) {
        int t = (tid >= st) ? sc[tid - st] : 0;
        __syncthreads();
        sc[tid] += t;
        __syncthreads();
    }
    int excl = sc[tid] - s;
    int c0 = obase + excl;
    int c1 = c0 + v0;
    cur[2 * tid] = c0;
    cur[2 * tid + 1] = c1;
    int n0 = node_base + 2 * tid;
    if (n0 < NN)     { deg[r * NN + n0] = v0;     offs[r * NN + n0] = c0; }
    if (n0 + 1 < NN) { deg[r * NN + n0 + 1] = v1; offs[r * NN + n0 + 1] = c1; }
    __syncthreads();
    for (int i = tid; i < count; i += 256) {
        uint p = pp[i];
        int pos = atomicAdd(&cur[p & 511], 1);
        srclist[pos] = (int)(p >> 9);
    }
}

// ---------------- merged prep: f2bf(x) + pack Bt1 + pack Bt2 + bias sums ----------------
#define F2B_BLKS 6250   // NN*DIN/4 / 256
__global__ __launch_bounds__(256) void prep_kernel(
    const float* __restrict__ x, ushort* __restrict__ xb,
    const float* __restrict__ ws1, const float* __restrict__ wn1, ushort* __restrict__ Bt1,
    const float* __restrict__ ws2, const float* __restrict__ wn2, ushort* __restrict__ Bt2,
    const float* __restrict__ b1, float* __restrict__ bsum1,
    const float* __restrict__ b2, float* __restrict__ bsum2) {
    int blk = blockIdx.x, tid = threadIdx.x;
    if (blk < F2B_BLKS) {
        int t = blk * 256 + tid;   // < 1.6M, exact
        float4 v = *(const float4*)(x + (size_t)t * 4);
        uint2 p;
        p.x = (uint)f2bf(v.x) | ((uint)f2bf(v.y) << 16);
        p.y = (uint)f2bf(v.z) | ((uint)f2bf(v.w) << 16);
        *(uint2*)(xb + (size_t)t * 4) = p;
    } else if (blk < F2B_BLKS + 512) {
        int t = (blk - F2B_BLKS) * 256 + tid;  // < 256*512
        int n = t >> 9, k = t & 511;
        int b = k >> 7, kk = k & 127;
        float v;
        if (b == 0)
            v = ws1[kk * 256 + n] + ws1[128 * 256 + kk * 256 + n] + ws1[2 * 128 * 256 + kk * 256 + n];
        else
            v = wn1[(size_t)(b - 1) * 128 * 256 + kk * 256 + n];
        Bt1[t] = f2bf(v);
    } else if (blk < F2B_BLKS + 1024) {
        int t = (blk - F2B_BLKS - 512) * 256 + tid;  // < 512*256
        int n = t >> 8, k = t & 255;
        int c = n >> 7, j = n & 127;
        float v;
        if (c == 0)
            v = ws2[k * 128 + j] + ws2[256 * 128 + k * 128 + j] + ws2[2 * 256 * 128 + k * 128 + j];
        else
            v = wn2[(size_t)(c - 1) * 256 * 128 + k * 128 + j];
        Bt2[t] = f2bf(v);
    } else {
        if (tid < DHID) bsum1[tid] = b1[tid] + b1[DHID + tid] + b1[2 * DHID + tid];
        if (tid < DOUT) bsum2[tid] = b2[tid] + b2[DOUT + tid] + b2[2 * DOUT + tid];
    }
}

// ---------------- merged gather-mean: one wave per node, 3 relations ----------------
// lane = g*16 + c: g = neighbor slot 0..3, c = 16B column chunk 0..15.
// 8 edges per inner iteration (two independent uint4 loads in flight).
// PHASE 0: write bf16 agg rows per relation. PHASE 1: out += sum_r mean_r (one fp32 RMW).
template <int PHASE>
__global__ __launch_bounds__(256) void gather3(
    const ushort* __restrict__ f0, const ushort* __restrict__ f1,
    const ushort* __restrict__ f2, const int* __restrict__ offs,
    const int* __restrict__ deg, const int* __restrict__ srclist,
    ushort* __restrict__ ob, float* __restrict__ of) {
    int node = blockIdx.x * 4 + (threadIdx.x >> 6);
    if (node >= NN) return;
    int lane = threadIdx.x & 63;
    int g = lane >> 4, c = lane & 15;
    float2 msum[4];
#pragma unroll
    for (int k = 0; k < 4; ++k) msum[k] = make_float2(0.f, 0.f);

    for (int r = 0; r < NREL; ++r) {
        const ushort* feat = (r == 0) ? f0 : (r == 1) ? f1 : f2;
        int beg = offs[r * NN + node];
        int d = deg[r * NN + node];
        float2 ac[4];
#pragma unroll
        for (int k = 0; k < 4; ++k) ac[k] = make_float2(0.f, 0.f);

        for (int i0 = 0; i0 < d; i0 += 64) {
            int m = d - i0;
            if (m > 64) m = 64;
            int sid_l = (lane < m) ? srclist[beg + i0 + lane] : 0;
            for (int j0 = 0; j0 < m; j0 += 8) {
                int j1 = j0 + g;
                int j2 = j0 + 4 + g;
                int s1 = __shfl(sid_l, (j1 < m) ? j1 : 0);
                int s2 = __shfl(sid_l, (j2 < m) ? j2 : 0);
                // unconditional loads (addresses always valid) -> 2 in flight
                uint4 v1 = *(const uint4*)(feat + (size_t)s1 * 128 + c * 8);
                uint4 v2 = *(const uint4*)(feat + (size_t)s2 * 128 + c * 8);
                if (j1 < m) {
                    acc2(ac[0], v1.x); acc2(ac[1], v1.y);
                    acc2(ac[2], v1.z); acc2(ac[3], v1.w);
                }
                if (j2 < m) {
                    acc2(ac[0], v2.x); acc2(ac[1], v2.y);
                    acc2(ac[2], v2.z); acc2(ac[3], v2.w);
                }
            }
        }
        // reduce the 4 g-groups (lanes c, c+16, c+32, c+48)
#pragma unroll
        for (int k = 0; k < 4; ++k) {
            ac[k].x += __shfl_xor(ac[k].x, 16);
            ac[k].y += __shfl_xor(ac[k].y, 16);
            ac[k].x += __shfl_xor(ac[k].x, 32);
            ac[k].y += __shfl_xor(ac[k].y, 32);
        }
        float inv = 1.f / fmaxf((float)d, 1.f);
        if (PHASE == 0) {
            if (g == 0) {
                uint4 pk;
                pk.x = (uint)f2bf(ac[0].x * inv) | ((uint)f2bf(ac[0].y * inv) << 16);
                pk.y = (uint)f2bf(ac[1].x * inv) | ((uint)f2bf(ac[1].y * inv) << 16);
                pk.z = (uint)f2bf(ac[2].x * inv) | ((uint)f2bf(ac[2].y * inv) << 16);
                pk.w = (uint)f2bf(ac[3].x * inv) | ((uint)f2bf(ac[3].y * inv) << 16);
                *(uint4*)(ob + (size_t)r * NN * DIN + (size_t)node * 128 + c * 8) = pk;
            }
        } else {
#pragma unroll
            for (int k = 0; k < 4; ++k) {
                msum[k].x += ac[k].x * inv;
                msum[k].y += ac[k].y * inv;
            }
        }
    }
    if (PHASE == 1 && g == 0) {
        float* po = of + (size_t)node * 128 + c * 8;
        float4 a = *(float4*)po;
        float4 b = *(float4*)(po + 4);
        a.x += msum[0].x; a.y += msum[0].y; a.z += msum[1].x; a.w += msum[1].y;
        b.x += msum[2].x; b.y += msum[2].y; b.z += msum[3].x; b.w += msum[3].y;
        *(float4*)po = a;
        *(float4*)(po + 4) = b;
    }
}

// ---------------- bf16 MFMA GEMM: 128x256 tile, BK=32, 512 threads (2x4 waves) ----------------
// LAYER 1: A = 4 k-blocked buffers [M][128] (K=512), C = H bf16 [M][256], bias+relu. grid (391,1)
// LAYER 2: A = H [M][256] (K=256), grid (391,2); global col gc = bn + local; buffer = gc>>7:
//          0 -> out fp32 [M][128] (+bias), 1..3 -> Y_r bf16 [M][128].
template <int LAYER>
__global__ __launch_bounds__(512) void gemm_mfma(
    const ushort* __restrict__ A0, const ushort* __restrict__ A1,
    const ushort* __restrict__ A2, const ushort* __restrict__ A3,
    const ushort* __restrict__ Bt, const float* __restrict__ bias,
    ushort* __restrict__ HO, float* __restrict__ CO,
    ushort* __restrict__ Y1, ushort* __restrict__ Y2, ushort* __restrict__ Y3) {
    constexpr int KTOT = (LAYER == 1) ? 512 : 256;
    constexpr int ASTRIDE = (LAYER == 1) ? 128 : 256;
    __shared__ __align__(16) ushort As[128 * 32];   // 8 KB
    __shared__ __align__(16) ushort Bs[256 * 32];   // 16 KB

    const int tid = threadIdx.x, lane = tid & 63, w = tid >> 6;
    const int wr = w >> 2, wc = w & 3;
    const int bm = blockIdx.x * 128;
    const int bn = blockIdx.y * 256;

    f32x4 acc[4][4];
#pragma unroll
    for (int m = 0; m < 4; ++m)
#pragma unroll
        for (int n = 0; n < 4; ++n) acc[m][n] = (f32x4){0.f, 0.f, 0.f, 0.f};

    const int srow = tid >> 2;          // staging row 0..127
    const int schunk = (tid & 3) * 8;   // ushort offset within row

    for (int k0 = 0; k0 < KTOT; k0 += 32) {
        const ushort* Ab = A0;
        int koff = k0;
        if (LAYER == 1) {
            int b = k0 >> 7;
            Ab = (b == 0) ? A0 : (b == 1) ? A1 : (b == 2) ? A2 : A3;
            koff = k0 & 127;
        }
        // A tile: 128 rows x 32, one issue (512 thr x 16B = 8KB)
        {
            const ushort* srcA = Ab + (size_t)(bm + srow) * ASTRIDE + koff + schunk;
            __builtin_amdgcn_global_load_lds((gptr_t)srcA, (lptr_t)(As + w * 512), 16, 0, 0);
        }
        // B tile: 256 rows x 32, two issues
#pragma unroll
        for (int i = 0; i < 2; ++i) {
            int row = i * 128 + srow;
            const ushort* srcB = Bt + (size_t)(bn + row) * KTOT + k0 + schunk;
            __builtin_amdgcn_global_load_lds((gptr_t)srcB, (lptr_t)(Bs + i * 4096 + w * 512), 16, 0, 0);
        }
        __syncthreads();

        const int r = lane & 15, g = lane >> 4;
        bf16x8 af[4], bg[4];
#pragma unroll
        for (int m = 0; m < 4; ++m)
            af[m] = *(const bf16x8*)&As[(wr * 64 + m * 16 + r) * 32 + g * 8];
#pragma unroll
        for (int n = 0; n < 4; ++n)
            bg[n] = *(const bf16x8*)&Bs[(wc * 64 + n * 16 + r) * 32 + g * 8];
#pragma unroll
        for (int m = 0; m < 4; ++m)
#pragma unroll
            for (int n = 0; n < 4; ++n)
                acc[m][n] = __builtin_amdgcn_mfma_f32_16x16x32_bf16(af[m], bg[n], acc[m][n], 0, 0, 0);
        __syncthreads();
    }

    const int r = lane & 15, g = lane >> 4;
    if (LAYER == 1) {
#pragma unroll
        for (int m = 0; m < 4; ++m)
#pragma unroll
            for (int v = 0; v < 4; ++v) {
                int gm = bm + wr * 64 + m * 16 + g * 4 + v;
                if (gm >= NN) continue;
#pragma unroll
                for (int n = 0; n < 4; ++n) {
                    int gn = wc * 64 + n * 16 + r;
                    float f = acc[m][n][v] + bias[gn];
                    f = fmaxf(f, 0.f);
                    HO[(size_t)gm * 256 + gn] = f2bf(f);
                }
            }
    } else {
        int buf = (bn >> 7) + (wc >> 1);          // wave-uniform: 0..3
        ushort* Y = (buf == 1) ? Y1 : (buf == 2) ? Y2 : Y3;
#pragma unroll
        for (int m = 0; m < 4; ++m)
#pragma unroll
            for (int v = 0; v < 4; ++v) {
                int gm = bm + wr * 64 + m * 16 + g * 4 + v;
                if (gm >= NN) continue;
#pragma unroll
                for (int n = 0; n < 4; ++n) {
                    int col = (wc & 1) * 64 + n * 16 + r;
                    if (buf == 0)
                        CO[(size_t)gm * 128 + col] = acc[m][n][v] + bias[col];
                    else
                        Y[(size_t)gm * 128 + col] = f2bf(acc[m][n][v]);
                }
            }
    }
}

// ---------------- launch ----------------
extern "C" void kernel_launch(void* const* d_in, const int* in_sizes, int n_in,
                              void* d_out, int out_size, void* d_ws, size_t ws_size,
                              hipStream_t stream) {
    const float* x        = (const float*)d_in[0];
    const int*   src      = (const int*)d_in[1];
    const int*   dst      = (const int*)d_in[2];
    const float* w_self1  = (const float*)d_in[3];
    const float* w_neigh1 = (const float*)d_in[4];
    const float* b1       = (const float*)d_in[5];
    const float* w_self2  = (const float*)d_in[6];
    const float* w_neigh2 = (const float*)d_in[7];
    const float* b2       = (const float*)d_in[8];
    float* out = (float*)d_out;

    char* ws = (char*)d_ws;
    size_t off = 0;
    auto alloc = [&](size_t bytes) {
        char* p = ws + off;
        off += (bytes + 255) & ~(size_t)255;
        return p;
    };
    int*    bcursor = (int*)alloc(NREL * NBUK * 4);
    int*    deg     = (int*)alloc(NREL * NN * 4);
    int*    offs    = (int*)alloc(NREL * NN * 4);
    int*    srclist = (int*)alloc((size_t)NREL * NBUK * CAP * 4);  // 9.6 MB, bucket regions
    float*  bsum1   = (float*)alloc(DHID * 4);
    float*  bsum2   = (float*)alloc(DOUT * 4);
    ushort* Bt1     = (ushort*)alloc((size_t)DHID * 512 * 2);
    ushort* Bt2     = (ushort*)alloc((size_t)512 * DHID * 2);
    ushort* xb      = (ushort*)alloc((size_t)NN * DIN * 2);
    ushort* aggb    = (ushort*)alloc((size_t)NREL * NN * DIN * 2);
    ushort* Hb      = (ushort*)alloc((size_t)NN * DHID * 2);
    (void)alloc(65536); // guard for GEMM tile over-reads past last M-block
    // pairs buffer aliases Hb: consumed by pass_b before layer-1 GEMM writes Hb.
    uint* pairs = (uint*)Hb;   // 3*98*8192*4 = 9.6 MB < 25.6 MB

    // ---- CSR build (bucketed counting sort; srclist in per-bucket regions)
    hipMemsetAsync(bcursor, 0, NREL * NBUK * 4, stream);
    pass_a<<<NREL * NCHK, 256, 0, stream>>>(src, dst, bcursor, pairs);
    pass_b<<<NREL * NBUK, 256, 0, stream>>>(pairs, bcursor, srclist, deg, offs);

    // ---- merged prep: xb, Bt1, Bt2, bias sums
    prep_kernel<<<F2B_BLKS + 1024 + 1, 256, 0, stream>>>(
        x, xb, w_self1, w_neigh1, Bt1, w_self2, w_neigh2, Bt2, b1, bsum1, b2, bsum2);

    int ggrid = (NN + 3) / 4;

    // ---- layer 1: agg_r = mean_r(x), all 3 relations in one kernel
    gather3<0><<<ggrid, 256, 0, stream>>>(xb, xb, xb, offs, deg, srclist, aggb, nullptr);
    // ---- layer 1 fused GEMM: H = relu([x|agg0|agg1|agg2] @ Bt1^T + bsum1)
    {
        dim3 grid((NN + 127) / 128, 1);
        gemm_mfma<1><<<grid, 512, 0, stream>>>(
            xb, aggb, aggb + (size_t)NN * DIN, aggb + (size_t)2 * NN * DIN,
            Bt1, bsum1, Hb, nullptr, nullptr, nullptr, nullptr);
    }
    // ---- layer 2 fused GEMM: [out | y0 | y1 | y2] = H @ Bt2^T (+bias on out)
    {
        dim3 grid((NN + 127) / 128, 2);
        gemm_mfma<2><<<grid, 512, 0, stream>>>(
            Hb, nullptr, nullptr, nullptr, Bt2, bsum2,
            nullptr, out, aggb, aggb + (size_t)NN * DIN, aggb + (size_t)2 * NN * DIN);
    }
    // ---- layer 2: out += sum_r mean_r(y_r), one RMW of out
    gather3<1><<<ggrid, 256, 0, stream>>>(
        aggb, aggb + (size_t)NN * DIN, aggb + (size_t)2 * NN * DIN,
        offs, deg, srclist, nullptr, out);
}

// Round 6
// 240.113 us; speedup vs baseline: 24.1989x; 1.0150x over previous
//
#include <hip/hip_runtime.h>

#define NN 50000
#define NREL 3
#define NE 500000
#define DIN 128
#define DHID 256
#define DOUT 128

#define NBUK 98          // ceil(50000/512) dst-buckets of 512 nodes
#define CAP 8192         // padded-slot capacity per bucket (E~6900, sd~100)
#define EPB 2048         // edges per pass-A block
#define NCHK ((NE + EPB - 1) / EPB)   // 245
#define PA_BLKS (NREL * NCHK)         // 735
#define F2B_BLKS 6250                 // NN*DIN/4/256
#define ZROW ((uint)NN << 8)          // scaled dummy -> zero row

typedef unsigned int uint;
typedef unsigned short ushort;
typedef __attribute__((ext_vector_type(8))) short bf16x8;
typedef __attribute__((ext_vector_type(4))) float f32x4;

using gptr_t = const __attribute__((address_space(1))) unsigned int*;
using lptr_t = __attribute__((address_space(3))) unsigned int*;

__device__ __forceinline__ ushort f2bf(float f) {
    uint u = __float_as_uint(f);
    uint r = (u + 0x7fffu + ((u >> 16) & 1u)) >> 16;
    return (ushort)r;
}
__device__ __forceinline__ void acc2(float2& a, uint u) {
    a.x += __uint_as_float(u << 16);
    a.y += __uint_as_float(u & 0xffff0000u);
}

// ---------------- pass A (bucket edges) + prep (fused grid) ----------------
__global__ __launch_bounds__(256) void pass_a_prep(
    const int* __restrict__ src, const int* __restrict__ dst,
    int* __restrict__ bcursor, uint* __restrict__ pairs,
    const float* __restrict__ x, ushort* __restrict__ xb,
    const float* __restrict__ ws1, const float* __restrict__ wn1, ushort* __restrict__ Bt1,
    const float* __restrict__ ws2, const float* __restrict__ wn2, ushort* __restrict__ Bt2,
    const float* __restrict__ b1, float* __restrict__ bsum1,
    const float* __restrict__ b2, float* __restrict__ bsum2,
    ushort* __restrict__ agg0, ushort* __restrict__ agg1, ushort* __restrict__ agg2) {
    int blk = blockIdx.x, tid = threadIdx.x;
    if (blk < PA_BLKS) {
        int r = blk / NCHK;
        int chunk = blk % NCHK;
        int e0 = chunk * EPB;
        int nedge = min(EPB, NE - e0);
        const int* S = src + (size_t)r * NE + e0;
        const int* D = dst + (size_t)r * NE + e0;
        __shared__ int cnt[NBUK], base[NBUK], cur[NBUK];
        if (tid < NBUK) { cnt[tid] = 0; cur[tid] = 0; }
        __syncthreads();
        uint pk[8];
        int bk[8];
        bool val[8];
#pragma unroll
        for (int j = 0; j < 8; ++j) {
            int e = j * 256 + tid;
            val[j] = e < nedge;
            int d = val[j] ? D[e] : 0;
            int s = val[j] ? S[e] : 0;
            bk[j] = d >> 9;
            pk[j] = ((uint)s << 9) | (uint)(d & 511);
            if (val[j]) atomicAdd(&cnt[bk[j]], 1);
        }
        __syncthreads();
        if (tid < NBUK) base[tid] = atomicAdd(&bcursor[r * NBUK + tid], cnt[tid]);
        __syncthreads();
#pragma unroll
        for (int j = 0; j < 8; ++j) {
            if (val[j]) {
                int slot = base[bk[j]] + atomicAdd(&cur[bk[j]], 1);
                if (slot < CAP) pairs[(size_t)(r * NBUK + bk[j]) * CAP + slot] = pk[j];
            }
        }
        return;
    }
    blk -= PA_BLKS;
    if (blk < F2B_BLKS) {
        int t = blk * 256 + tid;   // < NN*DIN/4, exact
        float4 v = *(const float4*)(x + (size_t)t * 4);
        uint2 p;
        p.x = (uint)f2bf(v.x) | ((uint)f2bf(v.y) << 16);
        p.y = (uint)f2bf(v.z) | ((uint)f2bf(v.w) << 16);
        *(uint2*)(xb + (size_t)t * 4) = p;
    } else if (blk < F2B_BLKS + 512) {
        int t = (blk - F2B_BLKS) * 256 + tid;  // < 256*512
        int n = t >> 9, k = t & 511;
        int b = k >> 7, kk = k & 127;
        float v;
        if (b == 0)
            v = ws1[kk * 256 + n] + ws1[128 * 256 + kk * 256 + n] + ws1[2 * 128 * 256 + kk * 256 + n];
        else
            v = wn1[(size_t)(b - 1) * 128 * 256 + kk * 256 + n];
        Bt1[t] = f2bf(v);
    } else if (blk < F2B_BLKS + 1024) {
        int t = (blk - F2B_BLKS - 512) * 256 + tid;  // < 512*256
        int n = t >> 8, k = t & 255;
        int c = n >> 7, j = n & 127;
        float v;
        if (c == 0)
            v = ws2[k * 128 + j] + ws2[256 * 128 + k * 128 + j] + ws2[2 * 256 * 128 + k * 128 + j];
        else
            v = wn2[(size_t)(c - 1) * 256 * 128 + k * 128 + j];
        Bt2[t] = f2bf(v);
    } else {
        // bias sums + zero rows (row NN of xb/agg0/agg1/agg2)
        if (tid < DHID) bsum1[tid] = b1[tid] + b1[DHID + tid] + b1[2 * DHID + tid];
        if (tid < DOUT) bsum2[tid] = b2[tid] + b2[DOUT + tid] + b2[2 * DOUT + tid];
        if (tid >= 192 && tid < 256) {
            int b = (tid - 192) >> 4, i = tid & 15;
            ushort* row = (b == 0) ? xb : (b == 1) ? agg0 : (b == 2) ? agg1 : agg2;
            uint4 z = {0u, 0u, 0u, 0u};
            *(uint4*)(row + (size_t)NN * 128 + i * 8) = z;
        }
    }
}

// ---------------- pass B: per-bucket CSR with 8-padded node slots ----------------
__global__ __launch_bounds__(256) void pass_b(const uint* __restrict__ pairs,
                                              const int* __restrict__ bcnt,
                                              uint* __restrict__ srclist,
                                              int* __restrict__ deg,
                                              int* __restrict__ offs) {
    int blk = blockIdx.x;
    int b = blk % NBUK;
    int r = blk / NBUK;
    int node_base = b * 512;
    int count = min(bcnt[blk], CAP);
    int obase = blk * CAP;
    const uint* pp = pairs + (size_t)blk * CAP;
    __shared__ int hist[512];
    __shared__ int cur[512];
    __shared__ int sc[256];
    int tid = threadIdx.x;
    hist[tid] = 0;
    hist[tid + 256] = 0;
    __syncthreads();
    for (int i = tid; i < count; i += 256) atomicAdd(&hist[pp[i] & 511], 1);
    __syncthreads();
    int v0 = hist[2 * tid], v1 = hist[2 * tid + 1];
    int p0 = (v0 + 7) & ~7;                 // padded slot sizes
    int p1 = (v1 + 7) & ~7;
    int s = p0 + p1;
    sc[tid] = s;
    __syncthreads();
    for (int st = 1; st < 256; st <<= 1) {
        int t = (tid >= st) ? sc[tid - st] : 0;
        __syncthreads();
        sc[tid] += t;
        __syncthreads();
    }
    int excl = sc[tid] - s;
    int c0 = obase + excl;
    int c1 = c0 + p0;
    cur[2 * tid] = c0;
    cur[2 * tid + 1] = c1;
    int n0 = node_base + 2 * tid;
    if (n0 < NN)     { deg[r * NN + n0] = v0;     offs[r * NN + n0] = c0; }
    if (n0 + 1 < NN) { deg[r * NN + n0 + 1] = v1; offs[r * NN + n0 + 1] = c1; }
    __syncthreads();
    for (int i = tid; i < count; i += 256) {
        uint p = pp[i];
        int pos = atomicAdd(&cur[p & 511], 1);
        srclist[pos] = (p >> 1) & ~255u;     // src*256 (pre-scaled byte offset)
    }
    __syncthreads();
    for (int i = v0; i < p0; ++i) srclist[c0 + i] = ZROW;
    for (int i = v1; i < p1; ++i) srclist[c1 + i] = ZROW;
}

// ---------------- merged gather-mean: one wave per node, branch-free inner loop ----------------
// lane = g*16 + c: g = edge slot 0..3, c = 16B column chunk. 8 edges/iter, 2 loads in flight.
template <int PHASE>
__global__ __launch_bounds__(256) void gather3(
    const ushort* __restrict__ f0, const ushort* __restrict__ f1,
    const ushort* __restrict__ f2, const int* __restrict__ offs,
    const int* __restrict__ deg, const uint* __restrict__ srclist,
    ushort* __restrict__ ob, float* __restrict__ of) {
    int node = blockIdx.x * 4 + (threadIdx.x >> 6);
    if (node >= NN) return;
    int lane = threadIdx.x & 63;
    int g = lane >> 4;
    uint c16 = (uint)(lane & 15) * 16;
    float2 msum[4];
#pragma unroll
    for (int k = 0; k < 4; ++k) msum[k] = make_float2(0.f, 0.f);

    for (int r = 0; r < NREL; ++r) {
        const char* feat = (const char*)((r == 0) ? f0 : (r == 1) ? f1 : f2);
        int beg = offs[r * NN + node];
        int d = deg[r * NN + node];
        int pd = (d + 7) & ~7;
        float2 ac[4];
#pragma unroll
        for (int k = 0; k < 4; ++k) ac[k] = make_float2(0.f, 0.f);

        for (int i0 = 0; i0 < pd; i0 += 64) {
            uint sid_l = srclist[beg + i0 + lane];
            int lim = pd - i0;
            if (lim > 64) lim = 64;
            for (int j0 = 0; j0 < lim; j0 += 8) {
                uint o1 = __shfl(sid_l, j0 + g) + c16;
                uint o2 = __shfl(sid_l, j0 + 4 + g) + c16;
                uint4 v1 = *(const uint4*)(feat + o1);
                uint4 v2 = *(const uint4*)(feat + o2);
                acc2(ac[0], v1.x); acc2(ac[1], v1.y);
                acc2(ac[2], v1.z); acc2(ac[3], v1.w);
                acc2(ac[0], v2.x); acc2(ac[1], v2.y);
                acc2(ac[2], v2.z); acc2(ac[3], v2.w);
            }
        }
        // reduce the 4 g-groups (lanes c, c+16, c+32, c+48)
#pragma unroll
        for (int k = 0; k < 4; ++k) {
            ac[k].x += __shfl_xor(ac[k].x, 16);
            ac[k].y += __shfl_xor(ac[k].y, 16);
            ac[k].x += __shfl_xor(ac[k].x, 32);
            ac[k].y += __shfl_xor(ac[k].y, 32);
        }
        float inv = 1.f / fmaxf((float)d, 1.f);
        if (PHASE == 0) {
            if (g == 0) {
                uint4 pk;
                pk.x = (uint)f2bf(ac[0].x * inv) | ((uint)f2bf(ac[0].y * inv) << 16);
                pk.y = (uint)f2bf(ac[1].x * inv) | ((uint)f2bf(ac[1].y * inv) << 16);
                pk.z = (uint)f2bf(ac[2].x * inv) | ((uint)f2bf(ac[2].y * inv) << 16);
                pk.w = (uint)f2bf(ac[3].x * inv) | ((uint)f2bf(ac[3].y * inv) << 16);
                *(uint4*)(ob + (size_t)r * (NN + 1) * DIN + (size_t)node * 128 + (c16 >> 1)) = pk;
            }
        } else {
#pragma unroll
            for (int k = 0; k < 4; ++k) {
                msum[k].x += ac[k].x * inv;
                msum[k].y += ac[k].y * inv;
            }
        }
    }
    if (PHASE == 1 && g == 0) {
        float* po = of + (size_t)node * 128 + (c16 >> 1);
        float4 a = *(float4*)po;
        float4 b = *(float4*)(po + 4);
        a.x += msum[0].x; a.y += msum[0].y; a.z += msum[1].x; a.w += msum[1].y;
        b.x += msum[2].x; b.y += msum[2].y; b.z += msum[3].x; b.w += msum[3].y;
        *(float4*)po = a;
        *(float4*)(po + 4) = b;
    }
}

// ---------------- bf16 MFMA GEMM: 128x256 tile, BK=32, 512 threads (2x4 waves) ----------------
// LAYER 1: A = 4 k-blocked buffers [M][128] (K=512), C = H bf16 [M][256], bias+relu. grid (391,1)
// LAYER 2: A = H [M][256] (K=256), grid (391,2); buffer = (bn>>7)+(wc>>1):
//          0 -> out fp32 [M][128] (+bias), 1..3 -> Y_r bf16 [M][128].
template <int LAYER>
__global__ __launch_bounds__(512) void gemm_mfma(
    const ushort* __restrict__ A0, const ushort* __restrict__ A1,
    const ushort* __restrict__ A2, const ushort* __restrict__ A3,
    const ushort* __restrict__ Bt, const float* __restrict__ bias,
    ushort* __restrict__ HO, float* __restrict__ CO,
    ushort* __restrict__ Y1, ushort* __restrict__ Y2, ushort* __restrict__ Y3) {
    constexpr int KTOT = (LAYER == 1) ? 512 : 256;
    constexpr int ASTRIDE = (LAYER == 1) ? 128 : 256;
    __shared__ __align__(16) ushort As[128 * 32];   // 8 KB
    __shared__ __align__(16) ushort Bs[256 * 32];   // 16 KB

    const int tid = threadIdx.x, lane = tid & 63, w = tid >> 6;
    const int wr = w >> 2, wc = w & 3;
    const int bm = blockIdx.x * 128;
    const int bn = blockIdx.y * 256;

    f32x4 acc[4][4];
#pragma unroll
    for (int m = 0; m < 4; ++m)
#pragma unroll
        for (int n = 0; n < 4; ++n) acc[m][n] = (f32x4){0.f, 0.f, 0.f, 0.f};

    const int srow = tid >> 2;          // staging row 0..127
    const int schunk = (tid & 3) * 8;   // ushort offset within row

    for (int k0 = 0; k0 < KTOT; k0 += 32) {
        const ushort* Ab = A0;
        int koff = k0;
        if (LAYER == 1) {
            int b = k0 >> 7;
            Ab = (b == 0) ? A0 : (b == 1) ? A1 : (b == 2) ? A2 : A3;
            koff = k0 & 127;
        }
        {
            const ushort* srcA = Ab + (size_t)(bm + srow) * ASTRIDE + koff + schunk;
            __builtin_amdgcn_global_load_lds((gptr_t)srcA, (lptr_t)(As + w * 512), 16, 0, 0);
        }
#pragma unroll
        for (int i = 0; i < 2; ++i) {
            int row = i * 128 + srow;
            const ushort* srcB = Bt + (size_t)(bn + row) * KTOT + k0 + schunk;
            __builtin_amdgcn_global_load_lds((gptr_t)srcB, (lptr_t)(Bs + i * 4096 + w * 512), 16, 0, 0);
        }
        __syncthreads();

        const int r = lane & 15, g = lane >> 4;
        bf16x8 af[4], bg[4];
#pragma unroll
        for (int m = 0; m < 4; ++m)
            af[m] = *(const bf16x8*)&As[(wr * 64 + m * 16 + r) * 32 + g * 8];
#pragma unroll
        for (int n = 0; n < 4; ++n)
            bg[n] = *(const bf16x8*)&Bs[(wc * 64 + n * 16 + r) * 32 + g * 8];
#pragma unroll
        for (int m = 0; m < 4; ++m)
#pragma unroll
            for (int n = 0; n < 4; ++n)
                acc[m][n] = __builtin_amdgcn_mfma_f32_16x16x32_bf16(af[m], bg[n], acc[m][n], 0, 0, 0);
        __syncthreads();
    }

    const int r = lane & 15, g = lane >> 4;
    if (LAYER == 1) {
#pragma unroll
        for (int m = 0; m < 4; ++m)
#pragma unroll
            for (int v = 0; v < 4; ++v) {
                int gm = bm + wr * 64 + m * 16 + g * 4 + v;
                if (gm >= NN) continue;
#pragma unroll
                for (int n = 0; n < 4; ++n) {
                    int gn = wc * 64 + n * 16 + r;
                    float f = acc[m][n][v] + bias[gn];
                    f = fmaxf(f, 0.f);
                    HO[(size_t)gm * 256 + gn] = f2bf(f);
                }
            }
    } else {
        int buf = (bn >> 7) + (wc >> 1);          // wave-uniform: 0..3
        ushort* Y = (buf == 1) ? Y1 : (buf == 2) ? Y2 : Y3;
#pragma unroll
        for (int m = 0; m < 4; ++m)
#pragma unroll
            for (int v = 0; v < 4; ++v) {
                int gm = bm + wr * 64 + m * 16 + g * 4 + v;
                if (gm >= NN) continue;
#pragma unroll
                for (int n = 0; n < 4; ++n) {
                    int col = (wc & 1) * 64 + n * 16 + r;
                    if (buf == 0)
                        CO[(size_t)gm * 128 + col] = acc[m][n][v] + bias[col];
                    else
                        Y[(size_t)gm * 128 + col] = f2bf(acc[m][n][v]);
                }
            }
    }
}

// ---------------- launch ----------------
extern "C" void kernel_launch(void* const* d_in, const int* in_sizes, int n_in,
                              void* d_out, int out_size, void* d_ws, size_t ws_size,
                              hipStream_t stream) {
    const float* x        = (const float*)d_in[0];
    const int*   src      = (const int*)d_in[1];
    const int*   dst      = (const int*)d_in[2];
    const float* w_self1  = (const float*)d_in[3];
    const float* w_neigh1 = (const float*)d_in[4];
    const float* b1       = (const float*)d_in[5];
    const float* w_self2  = (const float*)d_in[6];
    const float* w_neigh2 = (const float*)d_in[7];
    const float* b2       = (const float*)d_in[8];
    float* out = (float*)d_out;

    char* ws = (char*)d_ws;
    size_t off = 0;
    auto alloc = [&](size_t bytes) {
        char* p = ws + off;
        off += (bytes + 255) & ~(size_t)255;
        return p;
    };
    const size_t NROW = NN + 1;   // feature buffers carry a zero row at index NN
    int*    bcursor = (int*)alloc(NREL * NBUK * 4);
    int*    deg     = (int*)alloc(NREL * NN * 4);
    int*    offs    = (int*)alloc(NREL * NN * 4);
    uint*   srclist = (uint*)alloc(((size_t)NREL * NBUK * CAP + 256) * 4);  // +guard
    float*  bsum1   = (float*)alloc(DHID * 4);
    float*  bsum2   = (float*)alloc(DOUT * 4);
    ushort* Bt1     = (ushort*)alloc((size_t)DHID * 512 * 2);
    ushort* Bt2     = (ushort*)alloc((size_t)512 * DHID * 2);
    ushort* xb      = (ushort*)alloc(NROW * DIN * 2);
    ushort* aggb    = (ushort*)alloc((size_t)NREL * NROW * DIN * 2);
    ushort* Hb      = (ushort*)alloc((size_t)NN * DHID * 2);
    (void)alloc(65536); // guard for GEMM tile over-reads past last M-block
    // pairs buffer aliases Hb: consumed by pass_b before layer-1 GEMM writes Hb.
    uint* pairs = (uint*)Hb;   // 3*98*8192*4 = 9.6 MB < 25.6 MB
    ushort* agg0 = aggb;
    ushort* agg1 = aggb + NROW * DIN;
    ushort* agg2 = aggb + 2 * NROW * DIN;

    // ---- pass A (bucketing) + prep (xb/Bt1/Bt2/bias/zero-rows), one dispatch
    hipMemsetAsync(bcursor, 0, NREL * NBUK * 4, stream);
    pass_a_prep<<<PA_BLKS + F2B_BLKS + 1024 + 1, 256, 0, stream>>>(
        src, dst, bcursor, pairs,
        x, xb, w_self1, w_neigh1, Bt1, w_self2, w_neigh2, Bt2,
        b1, bsum1, b2, bsum2, agg0, agg1, agg2);
    // ---- pass B: padded per-bucket CSR
    pass_b<<<NREL * NBUK, 256, 0, stream>>>(pairs, bcursor, srclist, deg, offs);

    int ggrid = (NN + 3) / 4;

    // ---- layer 1: agg_r = mean_r(x), all 3 relations in one kernel
    gather3<0><<<ggrid, 256, 0, stream>>>(xb, xb, xb, offs, deg, srclist, aggb, nullptr);
    // ---- layer 1 fused GEMM: H = relu([x|agg0|agg1|agg2] @ Bt1^T + bsum1)
    {
        dim3 grid((NN + 127) / 128, 1);
        gemm_mfma<1><<<grid, 512, 0, stream>>>(
            xb, agg0, agg1, agg2, Bt1, bsum1, Hb, nullptr, nullptr, nullptr, nullptr);
    }
    // ---- layer 2 fused GEMM: [out | y0 | y1 | y2] = H @ Bt2^T (+bias on out)
    {
        dim3 grid((NN + 127) / 128, 2);
        gemm_mfma<2><<<grid, 512, 0, stream>>>(
            Hb, nullptr, nullptr, nullptr, Bt2, bsum2,
            nullptr, out, agg0, agg1, agg2);
    }
    // ---- layer 2: out += sum_r mean_r(y_r), one RMW of out
    gather3<1><<<ggrid, 256, 0, stream>>>(
        agg0, agg1, agg2, offs, deg, srclist, nullptr, out);
}

// Round 7
// 239.778 us; speedup vs baseline: 24.2327x; 1.0014x over previous
//
#include <hip/hip_runtime.h>

#define NN 50000
#define NREL 3
#define NE 500000
#define DIN 128
#define DHID 256
#define DOUT 128

#define NBUK 98          // ceil(50000/512) dst-buckets of 512 nodes
#define CAP 8192         // padded-slot capacity per bucket (E~6900, sd~100)
#define EPB 2048         // edges per pass-A block
#define NCHK ((NE + EPB - 1) / EPB)   // 245
#define PA_BLKS (NREL * NCHK)         // 735
#define F2B_BLKS 6250                 // NN*DIN/4/256
#define ZROW ((uint)NN << 8)          // scaled dummy -> zero row (byte offset)

typedef unsigned int uint;
typedef unsigned short ushort;
typedef __attribute__((ext_vector_type(8))) short bf16x8;
typedef __attribute__((ext_vector_type(4))) float f32x4;
typedef __attribute__((ext_vector_type(2))) float f32x2;

using gptr_t = const __attribute__((address_space(1))) unsigned int*;
using lptr_t = __attribute__((address_space(3))) unsigned int*;

__device__ __forceinline__ ushort f2bf(float f) {
    uint u = __float_as_uint(f);
    uint r = (u + 0x7fffu + ((u >> 16) & 1u)) >> 16;
    return (ushort)r;
}
__device__ __forceinline__ void acc2(f32x2& a, uint u) {
    f32x2 t;
    t.x = __uint_as_float(u << 16);
    t.y = __uint_as_float(u & 0xffff0000u);
    a += t;   // v_pk_add_f32
}
__device__ __forceinline__ void acc16(f32x2* a, uint4 v) {
    acc2(a[0], v.x); acc2(a[1], v.y); acc2(a[2], v.z); acc2(a[3], v.w);
}

// ---------------- pass A (bucket edges) + prep (fused grid) ----------------
__global__ __launch_bounds__(256) void pass_a_prep(
    const int* __restrict__ src, const int* __restrict__ dst,
    int* __restrict__ bcursor, uint* __restrict__ pairs,
    const float* __restrict__ x, ushort* __restrict__ xb,
    const float* __restrict__ ws1, const float* __restrict__ wn1, ushort* __restrict__ Bt1,
    const float* __restrict__ ws2, const float* __restrict__ wn2, ushort* __restrict__ Bt2,
    const float* __restrict__ b1, float* __restrict__ bsum1,
    const float* __restrict__ b2, float* __restrict__ bsum2,
    ushort* __restrict__ agg0, ushort* __restrict__ agg1, ushort* __restrict__ agg2) {
    int blk = blockIdx.x, tid = threadIdx.x;
    if (blk < PA_BLKS) {
        int r = blk / NCHK;
        int chunk = blk % NCHK;
        int e0 = chunk * EPB;
        int nedge = min(EPB, NE - e0);
        const int* S = src + (size_t)r * NE + e0;
        const int* D = dst + (size_t)r * NE + e0;
        __shared__ int cnt[NBUK], base[NBUK], cur[NBUK];
        if (tid < NBUK) { cnt[tid] = 0; cur[tid] = 0; }
        __syncthreads();
        uint pk[8];
        int bk[8];
        bool val[8];
#pragma unroll
        for (int j = 0; j < 8; ++j) {
            int e = j * 256 + tid;
            val[j] = e < nedge;
            int d = val[j] ? D[e] : 0;
            int s = val[j] ? S[e] : 0;
            bk[j] = d >> 9;
            pk[j] = ((uint)s << 9) | (uint)(d & 511);
            if (val[j]) atomicAdd(&cnt[bk[j]], 1);
        }
        __syncthreads();
        if (tid < NBUK) base[tid] = atomicAdd(&bcursor[r * NBUK + tid], cnt[tid]);
        __syncthreads();
#pragma unroll
        for (int j = 0; j < 8; ++j) {
            if (val[j]) {
                int slot = base[bk[j]] + atomicAdd(&cur[bk[j]], 1);
                if (slot < CAP) pairs[(size_t)(r * NBUK + bk[j]) * CAP + slot] = pk[j];
            }
        }
        return;
    }
    blk -= PA_BLKS;
    if (blk < F2B_BLKS) {
        int t = blk * 256 + tid;   // < NN*DIN/4, exact
        float4 v = *(const float4*)(x + (size_t)t * 4);
        uint2 p;
        p.x = (uint)f2bf(v.x) | ((uint)f2bf(v.y) << 16);
        p.y = (uint)f2bf(v.z) | ((uint)f2bf(v.w) << 16);
        *(uint2*)(xb + (size_t)t * 4) = p;
    } else if (blk < F2B_BLKS + 512) {
        int t = (blk - F2B_BLKS) * 256 + tid;  // < 256*512
        int n = t >> 9, k = t & 511;
        int b = k >> 7, kk = k & 127;
        float v;
        if (b == 0)
            v = ws1[kk * 256 + n] + ws1[128 * 256 + kk * 256 + n] + ws1[2 * 128 * 256 + kk * 256 + n];
        else
            v = wn1[(size_t)(b - 1) * 128 * 256 + kk * 256 + n];
        Bt1[t] = f2bf(v);
    } else if (blk < F2B_BLKS + 1024) {
        int t = (blk - F2B_BLKS - 512) * 256 + tid;  // < 512*256
        int n = t >> 8, k = t & 255;
        int c = n >> 7, j = n & 127;
        float v;
        if (c == 0)
            v = ws2[k * 128 + j] + ws2[256 * 128 + k * 128 + j] + ws2[2 * 256 * 128 + k * 128 + j];
        else
            v = wn2[(size_t)(c - 1) * 256 * 128 + k * 128 + j];
        Bt2[t] = f2bf(v);
    } else {
        // bias sums + zero rows (row NN of xb/agg0/agg1/agg2)
        if (tid < DHID) bsum1[tid] = b1[tid] + b1[DHID + tid] + b1[2 * DHID + tid];
        if (tid < DOUT) bsum2[tid] = b2[tid] + b2[DOUT + tid] + b2[2 * DOUT + tid];
        if (tid >= 192 && tid < 256) {
            int b = (tid - 192) >> 4, i = tid & 15;
            ushort* row = (b == 0) ? xb : (b == 1) ? agg0 : (b == 2) ? agg1 : agg2;
            uint4 z = {0u, 0u, 0u, 0u};
            *(uint4*)(row + (size_t)NN * 128 + i * 8) = z;
        }
    }
}

// ---------------- pass B: per-bucket CSR with 8-padded node slots ----------------
// nd[r*NN+n] = (deg, offs) packed.
__global__ __launch_bounds__(256) void pass_b(const uint* __restrict__ pairs,
                                              const int* __restrict__ bcnt,
                                              uint* __restrict__ srclist,
                                              int2* __restrict__ nd) {
    int blk = blockIdx.x;
    int b = blk % NBUK;
    int r = blk / NBUK;
    int node_base = b * 512;
    int count = min(bcnt[blk], CAP);
    int obase = blk * CAP;
    const uint* pp = pairs + (size_t)blk * CAP;
    __shared__ int hist[512];
    __shared__ int cur[512];
    __shared__ int sc[256];
    int tid = threadIdx.x;
    hist[tid] = 0;
    hist[tid + 256] = 0;
    __syncthreads();
    for (int i = tid; i < count; i += 256) atomicAdd(&hist[pp[i] & 511], 1);
    __syncthreads();
    int v0 = hist[2 * tid], v1 = hist[2 * tid + 1];
    int p0 = (v0 + 7) & ~7;                 // padded slot sizes
    int p1 = (v1 + 7) & ~7;
    int s = p0 + p1;
    sc[tid] = s;
    __syncthreads();
    for (int st = 1; st < 256; st <<= 1) {
        int t = (tid >= st) ? sc[tid - st] : 0;
        __syncthreads();
        sc[tid] += t;
        __syncthreads();
    }
    int excl = sc[tid] - s;
    int c0 = obase + excl;
    int c1 = c0 + p0;
    cur[2 * tid] = c0;
    cur[2 * tid + 1] = c1;
    int n0 = node_base + 2 * tid;
    if (n0 < NN)     nd[r * NN + n0]     = make_int2(v0, c0);
    if (n0 + 1 < NN) nd[r * NN + n0 + 1] = make_int2(v1, c1);
    __syncthreads();
    for (int i = tid; i < count; i += 256) {
        uint p = pp[i];
        int pos = atomicAdd(&cur[p & 511], 1);
        srclist[pos] = (p >> 1) & ~255u;     // src*256 (pre-scaled byte offset)
    }
    __syncthreads();
    for (int i = v0; i < p0; ++i) srclist[c0 + i] = ZROW;
    for (int i = v1; i < p1; ++i) srclist[c1 + i] = ZROW;
}

// ---------------- merged gather-mean: 3 relations interleaved, 6 loads in flight ----------------
// lane = g*16 + c: g = edge slot 0..3, c = 16B column chunk. Branch-free hot loop:
// exhausted relations clamp their address to the zero row (L1-hot, adds 0).
template <int PHASE>
__global__ __launch_bounds__(256) void gather3(
    const ushort* __restrict__ f0, const ushort* __restrict__ f1,
    const ushort* __restrict__ f2, const int2* __restrict__ nd,
    const uint* __restrict__ srclist,
    ushort* __restrict__ ob, float* __restrict__ of) {
    int node = blockIdx.x * 4 + (threadIdx.x >> 6);
    if (node >= NN) return;
    int lane = threadIdx.x & 63;
    int g = lane >> 4;
    uint c16 = (uint)(lane & 15) * 16;
    const char* fp0 = (const char*)f0;
    const char* fp1 = (const char*)f1;
    const char* fp2 = (const char*)f2;

    int2 q0 = nd[node];
    int2 q1 = nd[NN + node];
    int2 q2 = nd[2 * NN + node];
    int d0 = q0.x, d1 = q1.x, d2 = q2.x;
    int pd0 = (d0 + 7) & ~7, pd1 = (d1 + 7) & ~7, pd2 = (d2 + 7) & ~7;
    uint sid0 = srclist[q0.y + lane];
    uint sid1 = srclist[q1.y + lane];
    uint sid2 = srclist[q2.y + lane];

    f32x2 a0[4], a1[4], a2[4];
#pragma unroll
    for (int k = 0; k < 4; ++k) { a0[k] = 0.f; a1[k] = 0.f; a2[k] = 0.f; }

    uint zoff = ZROW + c16;
    int pmax = max(max(pd0, pd1), pd2);
    int pm64 = min(pmax, 64);
    for (int j0 = 0; j0 < pm64; j0 += 8) {
        uint oA = (j0 < pd0) ? (__shfl(sid0, j0 + g) + c16) : zoff;
        uint oB = (j0 < pd0) ? (__shfl(sid0, j0 + 4 + g) + c16) : zoff;
        uint oC = (j0 < pd1) ? (__shfl(sid1, j0 + g) + c16) : zoff;
        uint oD = (j0 < pd1) ? (__shfl(sid1, j0 + 4 + g) + c16) : zoff;
        uint oE = (j0 < pd2) ? (__shfl(sid2, j0 + g) + c16) : zoff;
        uint oF = (j0 < pd2) ? (__shfl(sid2, j0 + 4 + g) + c16) : zoff;
        uint4 vA = *(const uint4*)(fp0 + oA);
        uint4 vB = *(const uint4*)(fp0 + oB);
        uint4 vC = *(const uint4*)(fp1 + oC);
        uint4 vD = *(const uint4*)(fp1 + oD);
        uint4 vE = *(const uint4*)(fp2 + oE);
        uint4 vF = *(const uint4*)(fp2 + oF);
        acc16(a0, vA); acc16(a0, vB);
        acc16(a1, vC); acc16(a1, vD);
        acc16(a2, vE); acc16(a2, vF);
    }
    // rare tails (degree > 64)
    if (pmax > 64) {
        for (int i0 = 64; i0 < pd0; i0 += 64) {
            uint sl = srclist[q0.y + i0 + lane];
            int lim = min(pd0 - i0, 64);
            for (int j0 = 0; j0 < lim; j0 += 8) {
                uint u1 = __shfl(sl, j0 + g) + c16, u2 = __shfl(sl, j0 + 4 + g) + c16;
                acc16(a0, *(const uint4*)(fp0 + u1));
                acc16(a0, *(const uint4*)(fp0 + u2));
            }
        }
        for (int i0 = 64; i0 < pd1; i0 += 64) {
            uint sl = srclist[q1.y + i0 + lane];
            int lim = min(pd1 - i0, 64);
            for (int j0 = 0; j0 < lim; j0 += 8) {
                uint u1 = __shfl(sl, j0 + g) + c16, u2 = __shfl(sl, j0 + 4 + g) + c16;
                acc16(a1, *(const uint4*)(fp1 + u1));
                acc16(a1, *(const uint4*)(fp1 + u2));
            }
        }
        for (int i0 = 64; i0 < pd2; i0 += 64) {
            uint sl = srclist[q2.y + i0 + lane];
            int lim = min(pd2 - i0, 64);
            for (int j0 = 0; j0 < lim; j0 += 8) {
                uint u1 = __shfl(sl, j0 + g) + c16, u2 = __shfl(sl, j0 + 4 + g) + c16;
                acc16(a2, *(const uint4*)(fp2 + u1));
                acc16(a2, *(const uint4*)(fp2 + u2));
            }
        }
    }

    // reduce the 4 g-groups (lanes c, c+16, c+32, c+48)
#pragma unroll
    for (int k = 0; k < 4; ++k) {
        a0[k].x += __shfl_xor(a0[k].x, 16); a0[k].y += __shfl_xor(a0[k].y, 16);
        a0[k].x += __shfl_xor(a0[k].x, 32); a0[k].y += __shfl_xor(a0[k].y, 32);
        a1[k].x += __shfl_xor(a1[k].x, 16); a1[k].y += __shfl_xor(a1[k].y, 16);
        a1[k].x += __shfl_xor(a1[k].x, 32); a1[k].y += __shfl_xor(a1[k].y, 32);
        a2[k].x += __shfl_xor(a2[k].x, 16); a2[k].y += __shfl_xor(a2[k].y, 16);
        a2[k].x += __shfl_xor(a2[k].x, 32); a2[k].y += __shfl_xor(a2[k].y, 32);
    }
    float inv0 = 1.f / fmaxf((float)d0, 1.f);
    float inv1 = 1.f / fmaxf((float)d1, 1.f);
    float inv2 = 1.f / fmaxf((float)d2, 1.f);
    if (PHASE == 0) {
        if (g == 0) {
            size_t base = (size_t)node * 128 + (c16 >> 1);
            size_t rstride = (size_t)(NN + 1) * DIN;
            uint4 pk;
            pk.x = (uint)f2bf(a0[0].x * inv0) | ((uint)f2bf(a0[0].y * inv0) << 16);
            pk.y = (uint)f2bf(a0[1].x * inv0) | ((uint)f2bf(a0[1].y * inv0) << 16);
            pk.z = (uint)f2bf(a0[2].x * inv0) | ((uint)f2bf(a0[2].y * inv0) << 16);
            pk.w = (uint)f2bf(a0[3].x * inv0) | ((uint)f2bf(a0[3].y * inv0) << 16);
            *(uint4*)(ob + base) = pk;
            pk.x = (uint)f2bf(a1[0].x * inv1) | ((uint)f2bf(a1[0].y * inv1) << 16);
            pk.y = (uint)f2bf(a1[1].x * inv1) | ((uint)f2bf(a1[1].y * inv1) << 16);
            pk.z = (uint)f2bf(a1[2].x * inv1) | ((uint)f2bf(a1[2].y * inv1) << 16);
            pk.w = (uint)f2bf(a1[3].x * inv1) | ((uint)f2bf(a1[3].y * inv1) << 16);
            *(uint4*)(ob + rstride + base) = pk;
            pk.x = (uint)f2bf(a2[0].x * inv2) | ((uint)f2bf(a2[0].y * inv2) << 16);
            pk.y = (uint)f2bf(a2[1].x * inv2) | ((uint)f2bf(a2[1].y * inv2) << 16);
            pk.z = (uint)f2bf(a2[2].x * inv2) | ((uint)f2bf(a2[2].y * inv2) << 16);
            pk.w = (uint)f2bf(a2[3].x * inv2) | ((uint)f2bf(a2[3].y * inv2) << 16);
            *(uint4*)(ob + 2 * rstride + base) = pk;
        }
    } else {
        if (g == 0) {
            float* po = of + (size_t)node * 128 + (c16 >> 1);
            float4 a = *(float4*)po;
            float4 b = *(float4*)(po + 4);
            a.x += a0[0].x * inv0 + a1[0].x * inv1 + a2[0].x * inv2;
            a.y += a0[0].y * inv0 + a1[0].y * inv1 + a2[0].y * inv2;
            a.z += a0[1].x * inv0 + a1[1].x * inv1 + a2[1].x * inv2;
            a.w += a0[1].y * inv0 + a1[1].y * inv1 + a2[1].y * inv2;
            b.x += a0[2].x * inv0 + a1[2].x * inv1 + a2[2].x * inv2;
            b.y += a0[2].y * inv0 + a1[2].y * inv1 + a2[2].y * inv2;
            b.z += a0[3].x * inv0 + a1[3].x * inv1 + a2[3].x * inv2;
            b.w += a0[3].y * inv0 + a1[3].y * inv1 + a2[3].y * inv2;
            *(float4*)po = a;
            *(float4*)(po + 4) = b;
        }
    }
}

// ---------------- bf16 MFMA GEMM: 128x256 tile, BK=32, 512 threads (2x4 waves) ----------------
// LAYER 1: A = 4 k-blocked buffers [M][128] (K=512), C = H bf16 [M][256], bias+relu. grid (391,1)
// LAYER 2: A = H [M][256] (K=256), grid (391,2); buffer = (bn>>7)+(wc>>1):
//          0 -> out fp32 [M][128] (+bias), 1..3 -> Y_r bf16 [M][128].
template <int LAYER>
__global__ __launch_bounds__(512) void gemm_mfma(
    const ushort* __restrict__ A0, const ushort* __restrict__ A1,
    const ushort* __restrict__ A2, const ushort* __restrict__ A3,
    const ushort* __restrict__ Bt, const float* __restrict__ bias,
    ushort* __restrict__ HO, float* __restrict__ CO,
    ushort* __restrict__ Y1, ushort* __restrict__ Y2, ushort* __restrict__ Y3) {
    constexpr int KTOT = (LAYER == 1) ? 512 : 256;
    constexpr int ASTRIDE = (LAYER == 1) ? 128 : 256;
    __shared__ __align__(16) ushort As[128 * 32];   // 8 KB
    __shared__ __align__(16) ushort Bs[256 * 32];   // 16 KB

    const int tid = threadIdx.x, lane = tid & 63, w = tid >> 6;
    const int wr = w >> 2, wc = w & 3;
    const int bm = blockIdx.x * 128;
    const int bn = blockIdx.y * 256;

    f32x4 acc[4][4];
#pragma unroll
    for (int m = 0; m < 4; ++m)
#pragma unroll
        for (int n = 0; n < 4; ++n) acc[m][n] = (f32x4){0.f, 0.f, 0.f, 0.f};

    const int srow = tid >> 2;          // staging row 0..127
    const int schunk = (tid & 3) * 8;   // ushort offset within row

    for (int k0 = 0; k0 < KTOT; k0 += 32) {
        const ushort* Ab = A0;
        int koff = k0;
        if (LAYER == 1) {
            int b = k0 >> 7;
            Ab = (b == 0) ? A0 : (b == 1) ? A1 : (b == 2) ? A2 : A3;
            koff = k0 & 127;
        }
        {
            const ushort* srcA = Ab + (size_t)(bm + srow) * ASTRIDE + koff + schunk;
            __builtin_amdgcn_global_load_lds((gptr_t)srcA, (lptr_t)(As + w * 512), 16, 0, 0);
        }
#pragma unroll
        for (int i = 0; i < 2; ++i) {
            int row = i * 128 + srow;
            const ushort* srcB = Bt + (size_t)(bn + row) * KTOT + k0 + schunk;
            __builtin_amdgcn_global_load_lds((gptr_t)srcB, (lptr_t)(Bs + i * 4096 + w * 512), 16, 0, 0);
        }
        __syncthreads();

        const int r = lane & 15, g = lane >> 4;
        bf16x8 af[4], bg[4];
#pragma unroll
        for (int m = 0; m < 4; ++m)
            af[m] = *(const bf16x8*)&As[(wr * 64 + m * 16 + r) * 32 + g * 8];
#pragma unroll
        for (int n = 0; n < 4; ++n)
            bg[n] = *(const bf16x8*)&Bs[(wc * 64 + n * 16 + r) * 32 + g * 8];
#pragma unroll
        for (int m = 0; m < 4; ++m)
#pragma unroll
            for (int n = 0; n < 4; ++n)
                acc[m][n] = __builtin_amdgcn_mfma_f32_16x16x32_bf16(af[m], bg[n], acc[m][n], 0, 0, 0);
        __syncthreads();
    }

    const int r = lane & 15, g = lane >> 4;
    if (LAYER == 1) {
#pragma unroll
        for (int m = 0; m < 4; ++m)
#pragma unroll
            for (int v = 0; v < 4; ++v) {
                int gm = bm + wr * 64 + m * 16 + g * 4 + v;
                if (gm >= NN) continue;
#pragma unroll
                for (int n = 0; n < 4; ++n) {
                    int gn = wc * 64 + n * 16 + r;
                    float f = acc[m][n][v] + bias[gn];
                    f = fmaxf(f, 0.f);
                    HO[(size_t)gm * 256 + gn] = f2bf(f);
                }
            }
    } else {
        int buf = (bn >> 7) + (wc >> 1);          // wave-uniform: 0..3
        ushort* Y = (buf == 1) ? Y1 : (buf == 2) ? Y2 : Y3;
#pragma unroll
        for (int m = 0; m < 4; ++m)
#pragma unroll
            for (int v = 0; v < 4; ++v) {
                int gm = bm + wr * 64 + m * 16 + g * 4 + v;
                if (gm >= NN) continue;
#pragma unroll
                for (int n = 0; n < 4; ++n) {
                    int col = (wc & 1) * 64 + n * 16 + r;
                    if (buf == 0)
                        CO[(size_t)gm * 128 + col] = acc[m][n][v] + bias[col];
                    else
                        Y[(size_t)gm * 128 + col] = f2bf(acc[m][n][v]);
                }
            }
    }
}

// ---------------- launch ----------------
extern "C" void kernel_launch(void* const* d_in, const int* in_sizes, int n_in,
                              void* d_out, int out_size, void* d_ws, size_t ws_size,
                              hipStream_t stream) {
    const float* x        = (const float*)d_in[0];
    const int*   src      = (const int*)d_in[1];
    const int*   dst      = (const int*)d_in[2];
    const float* w_self1  = (const float*)d_in[3];
    const float* w_neigh1 = (const float*)d_in[4];
    const float* b1       = (const float*)d_in[5];
    const float* w_self2  = (const float*)d_in[6];
    const float* w_neigh2 = (const float*)d_in[7];
    const float* b2       = (const float*)d_in[8];
    float* out = (float*)d_out;

    char* ws = (char*)d_ws;
    size_t off = 0;
    auto alloc = [&](size_t bytes) {
        char* p = ws + off;
        off += (bytes + 255) & ~(size_t)255;
        return p;
    };
    const size_t NROW = NN + 1;   // feature buffers carry a zero row at index NN
    int*    bcursor = (int*)alloc(NREL * NBUK * 4);
    int2*   nd      = (int2*)alloc((size_t)NREL * NN * 8);
    uint*   srclist = (uint*)alloc(((size_t)NREL * NBUK * CAP + 256) * 4);  // +guard
    float*  bsum1   = (float*)alloc(DHID * 4);
    float*  bsum2   = (float*)alloc(DOUT * 4);
    ushort* Bt1     = (ushort*)alloc((size_t)DHID * 512 * 2);
    ushort* Bt2     = (ushort*)alloc((size_t)512 * DHID * 2);
    ushort* xb      = (ushort*)alloc(NROW * DIN * 2);
    ushort* aggb    = (ushort*)alloc((size_t)NREL * NROW * DIN * 2);
    ushort* Hb      = (ushort*)alloc((size_t)NN * DHID * 2);
    (void)alloc(65536); // guard for GEMM tile over-reads past last M-block
    // pairs buffer aliases Hb: consumed by pass_b before layer-1 GEMM writes Hb.
    uint* pairs = (uint*)Hb;   // 3*98*8192*4 = 9.6 MB < 25.6 MB
    ushort* agg0 = aggb;
    ushort* agg1 = aggb + NROW * DIN;
    ushort* agg2 = aggb + 2 * NROW * DIN;

    // ---- pass A (bucketing) + prep (xb/Bt1/Bt2/bias/zero-rows), one dispatch
    hipMemsetAsync(bcursor, 0, NREL * NBUK * 4, stream);
    pass_a_prep<<<PA_BLKS + F2B_BLKS + 1024 + 1, 256, 0, stream>>>(
        src, dst, bcursor, pairs,
        x, xb, w_self1, w_neigh1, Bt1, w_self2, w_neigh2, Bt2,
        b1, bsum1, b2, bsum2, agg0, agg1, agg2);
    // ---- pass B: padded per-bucket CSR
    pass_b<<<NREL * NBUK, 256, 0, stream>>>(pairs, bcursor, srclist, nd);

    int ggrid = (NN + 3) / 4;

    // ---- layer 1: agg_r = mean_r(x), all 3 relations interleaved in one kernel
    gather3<0><<<ggrid, 256, 0, stream>>>(xb, xb, xb, nd, srclist, aggb, nullptr);
    // ---- layer 1 fused GEMM: H = relu([x|agg0|agg1|agg2] @ Bt1^T + bsum1)
    {
        dim3 grid((NN + 127) / 128, 1);
        gemm_mfma<1><<<grid, 512, 0, stream>>>(
            xb, agg0, agg1, agg2, Bt1, bsum1, Hb, nullptr, nullptr, nullptr, nullptr);
    }
    // ---- layer 2 fused GEMM: [out | y0 | y1 | y2] = H @ Bt2^T (+bias on out)
    {
        dim3 grid((NN + 127) / 128, 2);
        gemm_mfma<2><<<grid, 512, 0, stream>>>(
            Hb, nullptr, nullptr, nullptr, Bt2, bsum2,
            nullptr, out, agg0, agg1, agg2);
    }
    // ---- layer 2: out += sum_r mean_r(y_r), one RMW of out
    gather3<1><<<ggrid, 256, 0, stream>>>(
        agg0, agg1, agg2, nd, srclist, nullptr, out);
}